// Round 10
// baseline (363.473 us; speedup 1.0000x reference)
//
#include <hip/hip_runtime.h>
#include <stdint.h>

// ---------------------------------------------------------------------------
// FineReviewDecoderAttention: compact active reviews -> cvt f32->bf16 (Q
// plain; K/V compacted) -> q/k/v proj (bf16 MFMA GEMM, counted-vmcnt
// 2-buffer pipeline + proven T2 swizzle, chunked XCD swizzle for compacted
// grids) -> fused attention -> out proj.  B=32 Q=128 D=1024 H=16 d=64 R=20.
// Delta vs round 22 (FAILED NaN, reg-staged A; unexplained after full ledger
// re-audit -> REVERTED to round-21 base, 269.3us passed): two safe levers:
//  (1) attn2 __launch_bounds__(512,4) -> (512,6): LDS (48KB) and threads
//      allow 3 blocks/CU but the old bound requested only 2.  VGPR 64 < 85
//      cap -> no spill.  +50% resident waves on a latency-bound kernel.
//  (2) Q projection moved onto the proven cvt+ADT=1 chain (pack2 RNE =
//      bit-identical to the old in-loop cvtpk): cvt_bf16(query->act, 8MB)
//      + gemm_bt<1,1,1,0> (0-conflict 32KB path).  ADT=0 path no longer
//      instantiated.  act reused serially: Qcvt,Qgemm,Kcvt,Kgemm,Vcvt,Vgemm.
// Everything else identical to round 21.
// ---------------------------------------------------------------------------

typedef __attribute__((ext_vector_type(8))) short bf16x8;
typedef __attribute__((ext_vector_type(4))) float f32x4;
typedef __attribute__((ext_vector_type(4))) unsigned int u32x4;
typedef __attribute__((address_space(1))) const unsigned int as1_t;
typedef __attribute__((address_space(3))) unsigned int as3_t;

#define DEVI static __device__ __forceinline__

DEVI unsigned short f2bf(float f) {  // RNE f32->bf16 (finite inputs)
  unsigned int u = __float_as_uint(f);
  u += 0x7fffu + ((u >> 16) & 1u);
  return (unsigned short)(u >> 16);
}
DEVI unsigned int pack2(float a, float b) {
  return (unsigned int)f2bf(a) | ((unsigned int)f2bf(b) << 16);
}
// Round-half-up bf16 pair pack (proven rounds 7-21): a -> lo16, b -> hi16.
DEVI unsigned int pk2_rhu(float a, float b) {
  unsigned int ua = __float_as_uint(a) + 0x8000u;
  unsigned int ub = __float_as_uint(b) + 0x8000u;
  return (ua >> 16) | (ub & 0xffff0000u);
}

DEVI void gload_lds16(const void* g, void* l) {
  __builtin_amdgcn_global_load_lds((as1_t*)g, (as3_t*)l, 16, 0, 0);
}

DEVI float fast_tanh(float x) {  // round-5-proven form
  float ax = fabsf(x);
  float e = __expf(2.0f * ax);
  float r = __builtin_fmaf(-2.0f, __builtin_amdgcn_rcpf(e + 1.0f), 1.0f);
  return copysignf(r, x);
}

// ------------------------- weight f32 -> bf16 ------------------------------
__global__ void cvt_w4(const float* __restrict__ w0, const float* __restrict__ w1,
                       const float* __restrict__ w2, const float* __restrict__ w3,
                       unsigned short* __restrict__ o0, unsigned short* __restrict__ o1,
                       unsigned short* __restrict__ o2, unsigned short* __restrict__ o3) {
  int i = blockIdx.x * 256 + threadIdx.x;
  if (i >= 262144) return;
  f32x4 v;
  uint2 a;
  v = ((const f32x4*)w0)[i]; a.x = pack2(v[0], v[1]); a.y = pack2(v[2], v[3]);
  *(uint2*)(o0 + 4 * (size_t)i) = a;
  v = ((const f32x4*)w1)[i]; a.x = pack2(v[0], v[1]); a.y = pack2(v[2], v[3]);
  *(uint2*)(o1 + 4 * (size_t)i) = a;
  v = ((const f32x4*)w2)[i]; a.x = pack2(v[0], v[1]); a.y = pack2(v[2], v[3]);
  *(uint2*)(o2 + 4 * (size_t)i) = a;
  v = ((const f32x4*)w3)[i]; a.x = pack2(v[0], v[1]); a.y = pack2(v[2], v[3]);
  *(uint2*)(o3 + 4 * (size_t)i) = a;
}

// --------------------- activation f32 -> bf16 stream -----------------------
__global__ void cvt_bf16(const float* __restrict__ src,
                         unsigned short* __restrict__ dst, int n8) {
  const int stride = (int)(gridDim.x * blockDim.x);
  for (int i = (int)(blockIdx.x * blockDim.x + threadIdx.x); i < n8; i += stride) {
    f32x4 a = ((const f32x4*)src)[2 * i];
    f32x4 b = ((const f32x4*)src)[2 * i + 1];
    u32x4 o = {pack2(a[0], a[1]), pack2(a[2], a[3]), pack2(b[0], b[1]), pack2(b[2], b[3])};
    ((u32x4*)dst)[i] = o;
  }
}

// ------------------- active-review slot compaction -------------------------
// out[0] = count; out[1..count] = ascending active slots s = b*20+r;
// out[1+count] = last active slot (pad; used only when count is odd).
// active(s): if batch b has any mask==0 -> (mask[s]==0), else all active.
// Mirrors attn2's bit-exact skip criterion (round-14).
__global__ void compact_rv(const int* __restrict__ mask, int* __restrict__ out) {
  const int lane = (int)threadIdx.x;  // 64 threads, 1 block
  __shared__ int azs[32];
  if (lane < 32) {
    int z = 0;
#pragma unroll
    for (int r = 0; r < 20; ++r) z |= (mask[lane * 20 + r] == 0) ? 1 : 0;
    azs[lane] = z;
  }
  __syncthreads();
  int base = 0;
  int lasts = 0;
  for (int it = 0; it < 10; ++it) {
    const int s = it * 64 + lane;
    const int bb = s / 20;
    const int actv = azs[bb] ? ((mask[s] == 0) ? 1 : 0) : 1;
    unsigned long long bal = __ballot(actv);
    const int off = (int)__popcll(bal & ((1ull << lane) - 1ull));
    if (actv) {
      out[1 + base + off] = s;
      lasts = s;
    }
    base += (int)__popcll(bal);
  }
#pragma unroll
  for (int d = 1; d < 64; d <<= 1) {
    int o = __shfl_xor(lasts, d);
    lasts = lasts > o ? lasts : o;
  }
  if (lane == 0) {
    out[0] = base;
    out[1 + base] = lasts;  // pad for odd count
  }
}

// --------------- compacted activation f32 -> bf16 (active slots) -----------
// dst is DENSE: compact position s holds slot cmp[1+s].  Converts
// round_up_even(cnt) slots so the odd-count pad tile reads valid data.
// Unit = 8 elements; slot = 64 rows x 1024 cols = 8192 units.
__global__ void cvt_act(const float* __restrict__ src,
                        unsigned short* __restrict__ dst,
                        const int* __restrict__ cmp) {
  const int cnt = cmp[0];
  const int n = ((cnt + 1) & ~1) * 8192;
  const int stride = (int)(gridDim.x * blockDim.x);
  for (int u = (int)(blockIdx.x * blockDim.x + threadIdx.x); u < n; u += stride) {
    const int s = u >> 13;
    const int e = u & 8191;
    const size_t so = (size_t)cmp[1 + s] * 65536 + (size_t)e * 8;
    f32x4 a = *(const f32x4*)(src + so);
    f32x4 b = *(const f32x4*)(src + so + 4);
    u32x4 o = {pack2(a[0], a[1]), pack2(a[2], a[3]),
               pack2(b[0], b[1]), pack2(b[2], b[3])};
    *(u32x4*)(dst + (size_t)u * 8) = o;
  }
}

// ---------------- C[m,n] = sum_k A[m,k]*W[n,k] + bias[n] -------------------
// OUT_MODE: 0 = f32 row-major, 1 = bf16 row-major, 2 = bf16 per-head V^T.
// A is bf16 (round-12-proven gload_lds path, 0-conflict tiles).  SC=1:
// epilogue x0.125.  CMP=1: A is DENSE-compacted (indexed by mt); C-writes
// go to absolute slots cs0/cs1 from cmp; active-aware chunked XCD swizzle;
// blocks beyond the active count exit early (uniform).
template <int OUT_MODE, int ADT, int SC, int CMP>
__global__ __launch_bounds__(256, 4) void gemm_bt(
    const void* __restrict__ Ain, const unsigned short* __restrict__ W,
    const float* __restrict__ bias, void* __restrict__ Cout, int N, int K, int nnt,
    const int* __restrict__ cmp) {
  __shared__ __align__(16) char smem[32768];
  char* Asb = smem;
  char* Bsb = smem + 16384;
  const int tid = (int)threadIdx.x;
  const int lane = tid & 63, wave = tid >> 6;
  const int lm = lane & 15, l4 = lane >> 4;
  const int nb = (int)gridDim.x;
  const int bx = (int)blockIdx.x;
  const int wr = wave >> 1, wc = wave & 1;

  // ---- tile mapping + output slot mapping (64-row slots: cs0, cs1) ----
  int mt, nt, cs0, cs1;
  if (CMP) {
    const int cnt = cmp[0];
    const int tiles = (cnt + 1) >> 1;   // ceil(cnt/2)
    if (bx >= tiles * 8) return;        // uniform exit before any barrier
    // chunked XCD swizzle (round-20-proven): XCD (= bx&7) owns a contiguous
    // lg chunk -> nt cycles within one mt, mt slices per XCD.
    const int lg = (bx & 7) * tiles + (bx >> 3);
    mt = lg / nnt;
    nt = lg % nnt;
    cs0 = cmp[1 + 2 * mt];
    cs1 = cmp[2 + 2 * mt];
  } else {
    const int lg = (bx & 7) * (nb >> 3) + (bx >> 3);
    mt = lg / nnt;
    nt = lg % nnt;
    cs0 = 2 * mt;
    cs1 = 2 * mt + 1;
  }

  f32x4 zero4 = {0.f, 0.f, 0.f, 0.f};
  f32x4 acc[4][4];
#pragma unroll
  for (int i = 0; i < 4; ++i)
#pragma unroll
    for (int j = 0; j < 4; ++j) acc[i][j] = zero4;

  // ---- staging mapping: row = tid>>2, 16B chunk = tid&3.
  // T2 swizzle: chunk (row,blk) lives at slot (row, blk ^ ((row>>1)&3)).
  // Linear LDS dest (tid*16) => pre-swizzle the GLOBAL column: scb.
  const int srow = tid >> 2, sblk = tid & 3;
  const int scb = sblk ^ ((srow >> 1) & 3);
  const unsigned short* wpg = W + (size_t)(nt * 128 + srow) * K + scb * 8;
  // fragment-read XOR key (proven): kx = (lm>>1)&3.
  const int kx = (lm >> 1) & 3;

  // ---- bf16-A path (round-12-proven): counted-vmcnt, swizzled tiles.
  // CMP=1: A is dense-compacted -> index by mt directly.
  const unsigned short* apg =
      (const unsigned short*)Ain + (size_t)(mt * 128 + srow) * K + scb * 8;
  const int NT = K >> 5;
#pragma unroll
  for (int t0 = 0; t0 < 2; ++t0) {
    const int kt = t0 * 32;
    gload_lds16(apg + kt, Asb + t0 * 8192 + tid * 16);
    gload_lds16(apg + (size_t)64 * K + kt, Asb + t0 * 8192 + 4096 + tid * 16);
    gload_lds16(wpg + kt, Bsb + t0 * 8192 + tid * 16);
    gload_lds16(wpg + (size_t)64 * K + kt, Bsb + t0 * 8192 + 4096 + tid * 16);
  }
  int cur = 0;
  for (int t = 0; t < NT; ++t) {
    if (t + 1 < NT)
      asm volatile("s_waitcnt vmcnt(4)" ::: "memory");
    else
      asm volatile("s_waitcnt vmcnt(0)" ::: "memory");
    asm volatile("s_barrier" ::: "memory");
    bf16x8 af[4], bfr[4];
#pragma unroll
    for (int i = 0; i < 4; ++i)
      af[i] = *(const bf16x8*)(Asb + cur * 8192 + (wr * 64 + i * 16 + lm) * 64 +
                               ((l4 ^ kx) * 16));
#pragma unroll
    for (int j = 0; j < 4; ++j)
      bfr[j] = *(const bf16x8*)(Bsb + cur * 8192 + (wc * 64 + j * 16 + lm) * 64 +
                                ((l4 ^ kx) * 16));
#pragma unroll
    for (int i = 0; i < 4; ++i)
#pragma unroll
      for (int j = 0; j < 4; ++j)
        acc[i][j] = __builtin_amdgcn_mfma_f32_16x16x32_bf16(af[i], bfr[j], acc[i][j], 0, 0, 0);
    asm volatile("s_barrier" ::: "memory");
    if (t + 2 < NT) {
      const int kt = (t + 2) * 32;
      gload_lds16(apg + kt, Asb + cur * 8192 + tid * 16);
      gload_lds16(apg + (size_t)64 * K + kt, Asb + cur * 8192 + 4096 + tid * 16);
      gload_lds16(wpg + kt, Bsb + cur * 8192 + tid * 16);
      gload_lds16(wpg + (size_t)64 * K + kt, Bsb + cur * 8192 + 4096 + tid * 16);
    }
    cur ^= 1;
  }

  const int c0o = nt * 128 + wc * 64 + lm;
  float bb[4];
#pragma unroll
  for (int j = 0; j < 4; ++j) bb[j] = bias[c0o + j * 16];
  const int mslot = wr ? cs1 : cs0;  // this wave's 64-row output slot

  if (OUT_MODE < 2) {
#pragma unroll
    for (int i = 0; i < 4; ++i)
#pragma unroll
      for (int j = 0; j < 4; ++j)
#pragma unroll
        for (int p = 0; p < 4; ++p) {
          size_t grow = (size_t)mslot * 64 + (l4 * 4 + i * 16 + p);
          size_t idx = grow * N + (size_t)(c0o + j * 16);
          float v = acc[i][j][p] + bb[j];
          if (SC) v *= 0.125f;  // exact exponent shift; bf16(v/8) == bf16(v)/8
          if (OUT_MODE == 1)
            ((unsigned short*)Cout)[idx] = f2bf(v);
          else
            ((float*)Cout)[idx] = v;
        }
  } else {
    // V^T per-head tiles: vt[(slot*16+h)*4096 + d*64 + t], t = i*16+l4*4+p
    const int hh = (nt * 128 + wc * 64) / 64;
    unsigned short* vt = (unsigned short*)Cout;
    const size_t base = ((size_t)mslot * 16 + hh) * 4096;
#pragma unroll
    for (int j = 0; j < 4; ++j) {
      const int d = lm + j * 16;
#pragma unroll
      for (int i = 0; i < 4; ++i) {
        uint2 wv;
        wv.x = pack2(acc[i][j][0] + bb[j], acc[i][j][1] + bb[j]);
        wv.y = pack2(acc[i][j][2] + bb[j], acc[i][j][3] + bb[j]);
        *(uint2*)(vt + base + (size_t)d * 64 + i * 16 + l4 * 4) = wv;
      }
    }
  }
}

// ----------------------------- fused attention -----------------------------
// One block per (h, b); 8 waves, wave w owns q rows [16w,16w+16).
// Swapped-operand MFMAs so q = lane&15 everywhere; online softmax over r.
// LDS (48KB): kv_s[2][K,V] 32KB; pa_s 16KB; q/sa^T staging overlays.
// launch_bounds (512,6): LDS/threads allow 3 blocks/CU; old (512,4) capped
// residency at 2.  VGPR 64 < ~85 cap -> no spill expected.
// Active-review compaction: reviews with mask==1 (when any mask==0 exists in
// row b) have pooled weight exactly 0.0f (expf(-1e30 - max) underflows) ->
// skipped entirely.  Bitmask is uniform per block (depends only on b).
__global__ __launch_bounds__(512, 6) void attn2(
    const unsigned short* __restrict__ qb, const unsigned short* __restrict__ kb,
    const unsigned short* __restrict__ vtg, const int* __restrict__ mask,
    const int* __restrict__ mask2, const float* __restrict__ sa_a,
    const float* __restrict__ sa_b, unsigned short* __restrict__ merged) {
  const int h = (int)blockIdx.x;
  const int b = (int)blockIdx.y;
  const int tid = (int)threadIdx.x;
  const int lane = tid & 63, wave = tid >> 6;
  const int lm = lane & 15, l4 = lane >> 4;
  const int sw = (lm & 7) << 4;

  __shared__ unsigned short kv_s[2][2][64 * 64];  // [buf][0=K [t][d], 1=V^T [d][t]]
  __shared__ unsigned short pa_s[8 * 16 * 64];    // wave-private P/att rows

  char* kvb0 = (char*)kv_s;          // buf stride 16384; V^T at +8192
  char* qreg = (char*)kv_s + 16384;  // q staging region = buf1 (dead after hoist)
  char* satb = (char*)pa_s;          // sa^T staging (dead after hoist)

  // ---- active-review bitmask (uniform across the block) ----
  unsigned am = 0u;
#pragma unroll
  for (int rr = 0; rr < 20; ++rr)
    am |= (mask[b * 20 + rr] == 0) ? (1u << rr) : 0u;
  // az (= some review has mask==0) => only those reviews survive; else all.
  const unsigned act = am ? am : 0xFFFFFu;

  // ---- stage Q into qreg (pre-swizzled source columns) ----
#pragma unroll
  for (int s = 0; s < 2; ++s) {
    int idx = s * 512 + tid, row = idx >> 3, blk = idx & 7;
    int cb = blk ^ (row & 7);
    gload_lds16(qb + (size_t)(b * 128 + row) * 1024 + h * 64 + cb * 8, qreg + idx * 16);
  }
  // ---- stage sa^T into satb: sat[jj][d] = sa_a[d][jj], swizzled ----
#pragma unroll
  for (int s = 0; s < 8; ++s) {
    int idx = s * 512 + tid, jj = idx & 63, d = idx >> 6;
    *(unsigned short*)(satb + jj * 128 + ((d * 2) ^ ((jj & 7) << 4))) =
        f2bf(sa_a[d * 64 + jj]);
  }
  // ---- stage first ACTIVE review K/V into buf0 ----
  const int srow = tid >> 3, sblk = tid & 7;
  const int scb = sblk ^ (srow & 7);
  int r = (int)__builtin_ctz(act);
  unsigned rem = act & (act - 1u);
  gload_lds16(kb + ((size_t)(b * 20 + r) * 64 + srow) * 1024 + h * 64 + scb * 8,
              kvb0 + tid * 16);
  gload_lds16(vtg + ((size_t)(b * 20 + r) * 16 + h) * 4096 + srow * 64 + scb * 8,
              kvb0 + 8192 + tid * 16);

  f32x4 sbv[4];
#pragma unroll
  for (int i = 0; i < 4; ++i) sbv[i] = *(const f32x4*)(sa_b + i * 16 + l4 * 4);

  __syncthreads();  // qreg, satb, buf0 all visible

  // ---- hoist Q B-fragments and sa^T A-fragments to registers ----
  const char* qrp = qreg + (wave * 16 + lm) * 128;
  bf16x8 qf[2];
  qf[0] = *(const bf16x8*)(qrp + ((l4 * 16) ^ sw));
  qf[1] = *(const bf16x8*)(qrp + ((64 + l4 * 16) ^ sw));
  bf16x8 sfr[2][4];
#pragma unroll
  for (int kk = 0; kk < 2; ++kk)
#pragma unroll
    for (int i = 0; i < 4; ++i)
      sfr[kk][i] = *(const bf16x8*)(satb + (i * 16 + lm) * 128 +
                                    ((kk * 64 + l4 * 16) ^ sw));
  asm volatile("s_waitcnt lgkmcnt(0)" ::: "memory");  // hoist reads retired
  __syncthreads();  // all waves done -> qreg/satb reusable as buf1 / P-rows

  char* pw = (char*)pa_s + wave * 2048 + lm * 128;  // wave-private row q=lm

  f32x4 zero4 = {0.f, 0.f, 0.f, 0.f};
  f32x4 Pacc[4];
#pragma unroll
  for (int i = 0; i < 4; ++i) Pacc[i] = zero4;
  float m_run = -3.0e38f, s_run = 0.0f;

  int it = 0;
  for (;;) {
    const int pb = it & 1;
    if (it) __syncthreads();  // buf[pb] staged; all waves done with buf[1-pb]
    const int nr = rem ? (int)__builtin_ctz(rem) : -1;
    if (nr >= 0) {  // stage next active review (flies under this one's compute)
      const int nbuf = pb ^ 1;
      gload_lds16(kb + ((size_t)(b * 20 + nr) * 64 + srow) * 1024 + h * 64 + scb * 8,
                  kvb0 + nbuf * 16384 + tid * 16);
      gload_lds16(vtg + ((size_t)(b * 20 + nr) * 16 + h) * 4096 + srow * 64 + scb * 8,
                  kvb0 + nbuf * 16384 + 8192 + tid * 16);
    }
    const char* kbse = kvb0 + pb * 16384;
    const char* vbse = kvb0 + pb * 16384 + 8192;

    // ---- S^T = mfma(K, Q): rows t, col q (q pre-scaled by 1/8) ----
    f32x4 sc[4];
#pragma unroll
    for (int i = 0; i < 4; ++i) sc[i] = zero4;
    __builtin_amdgcn_s_setprio(1);
#pragma unroll
    for (int kk = 0; kk < 2; ++kk) {
      bf16x8 kf[4];
#pragma unroll
      for (int i = 0; i < 4; ++i)
        kf[i] = *(const bf16x8*)(kbse + (i * 16 + lm) * 128 + ((kk * 64 + l4 * 16) ^ sw));
#pragma unroll
      for (int i = 0; i < 4; ++i)
        sc[i] = __builtin_amdgcn_mfma_f32_16x16x32_bf16(kf[i], qf[kk], sc[i], 0, 0, 0);
    }
    __builtin_amdgcn_s_setprio(0);

    // ---- token mask (scores already scaled) + softmax over t ----
    const int mbase = (b * 20 + r) * 64;
#pragma unroll
    for (int i = 0; i < 4; ++i) {
      int4 m2 = *(const int4*)(mask2 + mbase + i * 16 + l4 * 4);
      sc[i][0] = (m2.x == 0) ? -1e20f : sc[i][0];
      sc[i][1] = (m2.y == 0) ? -1e20f : sc[i][1];
      sc[i][2] = (m2.z == 0) ? -1e20f : sc[i][2];
      sc[i][3] = (m2.w == 0) ? -1e20f : sc[i][3];
    }
    float mx = sc[0][0];
#pragma unroll
    for (int i = 0; i < 4; ++i)
#pragma unroll
      for (int p = 0; p < 4; ++p) mx = fmaxf(mx, sc[i][p]);
    mx = fmaxf(mx, __shfl_xor(mx, 16));
    mx = fmaxf(mx, __shfl_xor(mx, 32));
    float sum = 0.f;
#pragma unroll
    for (int i = 0; i < 4; ++i)
#pragma unroll
      for (int p = 0; p < 4; ++p) {
        float e = __expf(sc[i][p] - mx);
        sc[i][p] = e;
        sum += e;
      }
    sum += __shfl_xor(sum, 16);
    sum += __shfl_xor(sum, 32);
    const float pinv = __builtin_amdgcn_rcpf(sum);

    // ---- P -> wave-private LDS [q][t], packed 8B swizzled writes ----
#pragma unroll
    for (int i = 0; i < 4; ++i) {
      uint2 wv;
      wv.x = pk2_rhu(sc[i][0] * pinv, sc[i][1] * pinv);
      wv.y = pk2_rhu(sc[i][2] * pinv, sc[i][3] * pinv);
      *(uint2*)(pw + ((i * 32 + l4 * 8) ^ sw)) = wv;
    }

    // ---- att^T = mfma(V^T, P): rows d, col q ----
    f32x4 av[4];
#pragma unroll
    for (int i = 0; i < 4; ++i) av[i] = zero4;
    __builtin_amdgcn_s_setprio(1);
#pragma unroll
    for (int kk = 0; kk < 2; ++kk) {
      bf16x8 pf = *(const bf16x8*)(pw + ((kk * 64 + l4 * 16) ^ sw));
      bf16x8 vf[4];
#pragma unroll
      for (int i = 0; i < 4; ++i)
        vf[i] = *(const bf16x8*)(vbse + (i * 16 + lm) * 128 + ((kk * 64 + l4 * 16) ^ sw));
#pragma unroll
      for (int i = 0; i < 4; ++i)
        av[i] = __builtin_amdgcn_mfma_f32_16x16x32_bf16(vf[i], pf, av[i], 0, 0, 0);
    }
    __builtin_amdgcn_s_setprio(0);

    // ---- att -> same wave-private LDS [q][d] (P already consumed) ----
#pragma unroll
    for (int i = 0; i < 4; ++i) {
      uint2 wv;
      wv.x = pk2_rhu(av[i][0], av[i][1]);
      wv.y = pk2_rhu(av[i][2], av[i][3]);
      *(uint2*)(pw + ((i * 32 + l4 * 8) ^ sw)) = wv;
    }

    // ---- e^T = mfma(sa^T, att): rows jj, col q ----
    f32x4 ep[4];
#pragma unroll
    for (int i = 0; i < 4; ++i) ep[i] = zero4;
    __builtin_amdgcn_s_setprio(1);
#pragma unroll
    for (int kk = 0; kk < 2; ++kk) {
      bf16x8 afr = *(const bf16x8*)(pw + ((kk * 64 + l4 * 16) ^ sw));
#pragma unroll
      for (int i = 0; i < 4; ++i)
        ep[i] = __builtin_amdgcn_mfma_f32_16x16x32_bf16(sfr[kk][i], afr, ep[i], 0, 0, 0);
    }
    __builtin_amdgcn_s_setprio(0);
    float a = 0.f;
#pragma unroll
    for (int i = 0; i < 4; ++i)
#pragma unroll
      for (int p = 0; p < 4; ++p) a += fast_tanh(ep[i][p]) * sbv[i][p];
    a += __shfl_xor(a, 16);
    a += __shfl_xor(a, 32);

    // ---- exact online softmax update over active reviews ----
    // All surviving reviews have add_mask == 0, so e_r = a directly.
    const float e_r = a;
    const float mnew = fmaxf(m_run, e_r);
    const float scl = __expf(m_run - mnew);
    const float w = __expf(e_r - mnew);
    s_run = s_run * scl + w;
#pragma unroll
    for (int i = 0; i < 4; ++i)
#pragma unroll
      for (int p = 0; p < 4; ++p) Pacc[i][p] = Pacc[i][p] * scl + w * av[i][p];
    m_run = mnew;

    if (nr < 0) break;
    r = nr;
    rem &= rem - 1u;
    ++it;
  }

  // ---- merged[b*128+q][h*64+d] = bf16(Pacc / s) ----
  const float inv_s = __builtin_amdgcn_rcpf(s_run);
  unsigned short* mrow = merged + (size_t)(b * 128 + wave * 16 + lm) * 1024 + h * 64;
#pragma unroll
  for (int i = 0; i < 4; ++i) {
    uint2 o;
    o.x = pk2_rhu(Pacc[i][0] * inv_s, Pacc[i][1] * inv_s);
    o.y = pk2_rhu(Pacc[i][2] * inv_s, Pacc[i][3] * inv_s);
    *(uint2*)(mrow + i * 16 + l4 * 4) = o;
  }
}

// ---------------------------------------------------------------------------
extern "C" void kernel_launch(void* const* d_in, const int* in_sizes, int n_in,
                              void* d_out, int out_size, void* d_ws, size_t ws_size,
                              hipStream_t stream) {
  (void)in_sizes; (void)n_in; (void)out_size; (void)ws_size;
  const float* query = (const float*)d_in[0];
  const float* key   = (const float*)d_in[1];
  const float* value = (const float*)d_in[2];
  const int*   mask  = (const int*)d_in[3];
  const int*   mask2 = (const int*)d_in[4];
  const float* Wq = (const float*)d_in[5];
  const float* bq = (const float*)d_in[6];
  const float* Wk = (const float*)d_in[7];
  const float* bk = (const float*)d_in[8];
  const float* Wv = (const float*)d_in[9];
  const float* bv = (const float*)d_in[10];
  const float* Wo = (const float*)d_in[11];
  const float* bo = (const float*)d_in[12];
  const float* sa_a = (const float*)d_in[13];
  const float* sa_b = (const float*)d_in[14];

  char* ws = (char*)d_ws;
  size_t off = 0;
  auto carve = [&](size_t bytes) -> char* {
    char* p = ws + off;
    off += (bytes + 255) & ~(size_t)255;
    return p;
  };
  unsigned short* wq_b = (unsigned short*)carve((size_t)1024 * 1024 * 2);
  unsigned short* wk_b = (unsigned short*)carve((size_t)1024 * 1024 * 2);
  unsigned short* wv_b = (unsigned short*)carve((size_t)1024 * 1024 * 2);
  unsigned short* wo_b = (unsigned short*)carve((size_t)1024 * 1024 * 2);
  unsigned short* q_b  = (unsigned short*)carve((size_t)4096 * 1024 * 2);
  unsigned short* k_b  = (unsigned short*)carve((size_t)40960 * 1024 * 2);
  unsigned short* vt_g = (unsigned short*)carve((size_t)40960 * 1024 * 2);
  unsigned short* mrg  = (unsigned short*)carve((size_t)4096 * 1024 * 2);
  int* cmp = (int*)carve(4096);
  // shared compacted-activation buffer (reused Q, K, V serially; same-stream
  // ordering guarantees each GEMM consumes act before the next cvt rewrites
  // it).  Total ws ~264MB = round-1 fat-path footprint (proven available).
  unsigned short* act = (unsigned short*)carve((size_t)40960 * 1024 * 2);

  cvt_w4<<<1024, 256, 0, stream>>>(Wq, Wk, Wv, Wo, wq_b, wk_b, wv_b, wo_b);
  compact_rv<<<1, 64, 0, stream>>>(mask, cmp);

  // Q projection: plain cvt -> proven bf16-A GEMM (x0.125 epilogue)
  cvt_bf16<<<1024, 256, 0, stream>>>(query, act, 4096 * 1024 / 8);
  gemm_bt<1, 1, 1, 0><<<dim3(32 * 8), 256, 0, stream>>>(act, wq_b, bq, q_b, 1024, 1024, 8, cmp);

  // K projection: compacted cvt -> proven bf16-A GEMM (dense A, slot C-write)
  cvt_act<<<2048, 256, 0, stream>>>(key, act, cmp);
  gemm_bt<1, 1, 0, 1><<<dim3(320 * 8), 256, 0, stream>>>(act, wk_b, bk, k_b, 1024, 1024, 8, cmp);

  // V projection: same act buffer (K-GEMM already consumed it)
  cvt_act<<<2048, 256, 0, stream>>>(value, act, cmp);
  gemm_bt<2, 1, 0, 1><<<dim3(320 * 8), 256, 0, stream>>>(act, wv_b, bv, vt_g, 1024, 1024, 8, cmp);

  attn2<<<dim3(16, 32), 512, 0, stream>>>(q_b, k_b, vt_g, mask, mask2, sa_a, sa_b, mrg);

  // out projection: A (mrg) is bf16 -> proven bf16-A path
  gemm_bt<0, 1, 0, 0><<<dim3(32 * 8), 256, 0, stream>>>(mrg, wo_b, bo, d_out, 1024, 1024, 8, cmp);
}

// Round 11
// 266.841 us; speedup vs baseline: 1.3621x; 1.3621x over previous
//
#include <hip/hip_runtime.h>
#include <stdint.h>

// ---------------------------------------------------------------------------
// FineReviewDecoderAttention: compact active reviews -> cvt f32->bf16 (Q
// plain; K/V compacted) -> q/k/v proj (bf16 MFMA GEMM, counted-vmcnt
// 2-buffer pipeline + proven T2 swizzle, chunked XCD swizzle for compacted
// grids) -> fused attention -> out proj.  B=32 Q=128 D=1024 H=16 d=64 R=20.
// Delta vs round 23 (passed, 363.5us -- REGRESSION): attn2's (512,6) bound
// made the allocator squeeze VGPR 64->40 and spill (FETCH 95->339MB, dur
// 65->171us).  REVERT attn2 to the proven __launch_bounds__(512,4).
// Everything else kept from round 23: Q/K/V all on the proven 0-conflict
// bf16 ADT=1 GEMM; Q fed by plain cvt_bf16, K/V by compacted cvt_act
// (active slots only); chunked XCD swizzle on compacted grids; out-proj
// unchanged.  Expected: back to ~round-21 minus the Q-chain gain.
// ---------------------------------------------------------------------------

typedef __attribute__((ext_vector_type(8))) short bf16x8;
typedef __attribute__((ext_vector_type(4))) float f32x4;
typedef __attribute__((ext_vector_type(4))) unsigned int u32x4;
typedef __attribute__((address_space(1))) const unsigned int as1_t;
typedef __attribute__((address_space(3))) unsigned int as3_t;

#define DEVI static __device__ __forceinline__

DEVI unsigned short f2bf(float f) {  // RNE f32->bf16 (finite inputs)
  unsigned int u = __float_as_uint(f);
  u += 0x7fffu + ((u >> 16) & 1u);
  return (unsigned short)(u >> 16);
}
DEVI unsigned int pack2(float a, float b) {
  return (unsigned int)f2bf(a) | ((unsigned int)f2bf(b) << 16);
}
// Round-half-up bf16 pair pack (proven rounds 7-23): a -> lo16, b -> hi16.
DEVI unsigned int pk2_rhu(float a, float b) {
  unsigned int ua = __float_as_uint(a) + 0x8000u;
  unsigned int ub = __float_as_uint(b) + 0x8000u;
  return (ua >> 16) | (ub & 0xffff0000u);
}

DEVI void gload_lds16(const void* g, void* l) {
  __builtin_amdgcn_global_load_lds((as1_t*)g, (as3_t*)l, 16, 0, 0);
}

DEVI float fast_tanh(float x) {  // round-5-proven form
  float ax = fabsf(x);
  float e = __expf(2.0f * ax);
  float r = __builtin_fmaf(-2.0f, __builtin_amdgcn_rcpf(e + 1.0f), 1.0f);
  return copysignf(r, x);
}

// ------------------------- weight f32 -> bf16 ------------------------------
__global__ void cvt_w4(const float* __restrict__ w0, const float* __restrict__ w1,
                       const float* __restrict__ w2, const float* __restrict__ w3,
                       unsigned short* __restrict__ o0, unsigned short* __restrict__ o1,
                       unsigned short* __restrict__ o2, unsigned short* __restrict__ o3) {
  int i = blockIdx.x * 256 + threadIdx.x;
  if (i >= 262144) return;
  f32x4 v;
  uint2 a;
  v = ((const f32x4*)w0)[i]; a.x = pack2(v[0], v[1]); a.y = pack2(v[2], v[3]);
  *(uint2*)(o0 + 4 * (size_t)i) = a;
  v = ((const f32x4*)w1)[i]; a.x = pack2(v[0], v[1]); a.y = pack2(v[2], v[3]);
  *(uint2*)(o1 + 4 * (size_t)i) = a;
  v = ((const f32x4*)w2)[i]; a.x = pack2(v[0], v[1]); a.y = pack2(v[2], v[3]);
  *(uint2*)(o2 + 4 * (size_t)i) = a;
  v = ((const f32x4*)w3)[i]; a.x = pack2(v[0], v[1]); a.y = pack2(v[2], v[3]);
  *(uint2*)(o3 + 4 * (size_t)i) = a;
}

// --------------------- activation f32 -> bf16 stream -----------------------
__global__ void cvt_bf16(const float* __restrict__ src,
                         unsigned short* __restrict__ dst, int n8) {
  const int stride = (int)(gridDim.x * blockDim.x);
  for (int i = (int)(blockIdx.x * blockDim.x + threadIdx.x); i < n8; i += stride) {
    f32x4 a = ((const f32x4*)src)[2 * i];
    f32x4 b = ((const f32x4*)src)[2 * i + 1];
    u32x4 o = {pack2(a[0], a[1]), pack2(a[2], a[3]), pack2(b[0], b[1]), pack2(b[2], b[3])};
    ((u32x4*)dst)[i] = o;
  }
}

// ------------------- active-review slot compaction -------------------------
// out[0] = count; out[1..count] = ascending active slots s = b*20+r;
// out[1+count] = last active slot (pad; used only when count is odd).
// active(s): if batch b has any mask==0 -> (mask[s]==0), else all active.
// Mirrors attn2's bit-exact skip criterion (round-14).
__global__ void compact_rv(const int* __restrict__ mask, int* __restrict__ out) {
  const int lane = (int)threadIdx.x;  // 64 threads, 1 block
  __shared__ int azs[32];
  if (lane < 32) {
    int z = 0;
#pragma unroll
    for (int r = 0; r < 20; ++r) z |= (mask[lane * 20 + r] == 0) ? 1 : 0;
    azs[lane] = z;
  }
  __syncthreads();
  int base = 0;
  int lasts = 0;
  for (int it = 0; it < 10; ++it) {
    const int s = it * 64 + lane;
    const int bb = s / 20;
    const int actv = azs[bb] ? ((mask[s] == 0) ? 1 : 0) : 1;
    unsigned long long bal = __ballot(actv);
    const int off = (int)__popcll(bal & ((1ull << lane) - 1ull));
    if (actv) {
      out[1 + base + off] = s;
      lasts = s;
    }
    base += (int)__popcll(bal);
  }
#pragma unroll
  for (int d = 1; d < 64; d <<= 1) {
    int o = __shfl_xor(lasts, d);
    lasts = lasts > o ? lasts : o;
  }
  if (lane == 0) {
    out[0] = base;
    out[1 + base] = lasts;  // pad for odd count
  }
}

// --------------- compacted activation f32 -> bf16 (active slots) -----------
// dst is DENSE: compact position s holds slot cmp[1+s].  Converts
// round_up_even(cnt) slots so the odd-count pad tile reads valid data.
// Unit = 8 elements; slot = 64 rows x 1024 cols = 8192 units.
__global__ void cvt_act(const float* __restrict__ src,
                        unsigned short* __restrict__ dst,
                        const int* __restrict__ cmp) {
  const int cnt = cmp[0];
  const int n = ((cnt + 1) & ~1) * 8192;
  const int stride = (int)(gridDim.x * blockDim.x);
  for (int u = (int)(blockIdx.x * blockDim.x + threadIdx.x); u < n; u += stride) {
    const int s = u >> 13;
    const int e = u & 8191;
    const size_t so = (size_t)cmp[1 + s] * 65536 + (size_t)e * 8;
    f32x4 a = *(const f32x4*)(src + so);
    f32x4 b = *(const f32x4*)(src + so + 4);
    u32x4 o = {pack2(a[0], a[1]), pack2(a[2], a[3]),
               pack2(b[0], b[1]), pack2(b[2], b[3])};
    *(u32x4*)(dst + (size_t)u * 8) = o;
  }
}

// ---------------- C[m,n] = sum_k A[m,k]*W[n,k] + bias[n] -------------------
// OUT_MODE: 0 = f32 row-major, 1 = bf16 row-major, 2 = bf16 per-head V^T.
// A is bf16 (round-12-proven gload_lds path, 0-conflict tiles).  SC=1:
// epilogue x0.125.  CMP=1: A is DENSE-compacted (indexed by mt); C-writes
// go to absolute slots cs0/cs1 from cmp; active-aware chunked XCD swizzle;
// blocks beyond the active count exit early (uniform).
template <int OUT_MODE, int ADT, int SC, int CMP>
__global__ __launch_bounds__(256, 4) void gemm_bt(
    const void* __restrict__ Ain, const unsigned short* __restrict__ W,
    const float* __restrict__ bias, void* __restrict__ Cout, int N, int K, int nnt,
    const int* __restrict__ cmp) {
  __shared__ __align__(16) char smem[32768];
  char* Asb = smem;
  char* Bsb = smem + 16384;
  const int tid = (int)threadIdx.x;
  const int lane = tid & 63, wave = tid >> 6;
  const int lm = lane & 15, l4 = lane >> 4;
  const int nb = (int)gridDim.x;
  const int bx = (int)blockIdx.x;
  const int wr = wave >> 1, wc = wave & 1;

  // ---- tile mapping + output slot mapping (64-row slots: cs0, cs1) ----
  int mt, nt, cs0, cs1;
  if (CMP) {
    const int cnt = cmp[0];
    const int tiles = (cnt + 1) >> 1;   // ceil(cnt/2)
    if (bx >= tiles * 8) return;        // uniform exit before any barrier
    // chunked XCD swizzle (round-20-proven): XCD (= bx&7) owns a contiguous
    // lg chunk -> nt cycles within one mt, mt slices per XCD.
    const int lg = (bx & 7) * tiles + (bx >> 3);
    mt = lg / nnt;
    nt = lg % nnt;
    cs0 = cmp[1 + 2 * mt];
    cs1 = cmp[2 + 2 * mt];
  } else {
    const int lg = (bx & 7) * (nb >> 3) + (bx >> 3);
    mt = lg / nnt;
    nt = lg % nnt;
    cs0 = 2 * mt;
    cs1 = 2 * mt + 1;
  }

  f32x4 zero4 = {0.f, 0.f, 0.f, 0.f};
  f32x4 acc[4][4];
#pragma unroll
  for (int i = 0; i < 4; ++i)
#pragma unroll
    for (int j = 0; j < 4; ++j) acc[i][j] = zero4;

  // ---- staging mapping: row = tid>>2, 16B chunk = tid&3.
  // T2 swizzle: chunk (row,blk) lives at slot (row, blk ^ ((row>>1)&3)).
  // Linear LDS dest (tid*16) => pre-swizzle the GLOBAL column: scb.
  const int srow = tid >> 2, sblk = tid & 3;
  const int scb = sblk ^ ((srow >> 1) & 3);
  const unsigned short* wpg = W + (size_t)(nt * 128 + srow) * K + scb * 8;
  // fragment-read XOR key (proven): kx = (lm>>1)&3.
  const int kx = (lm >> 1) & 3;

  // ---- bf16-A path (round-12-proven): counted-vmcnt, swizzled tiles.
  // CMP=1: A is dense-compacted -> index by mt directly.
  const unsigned short* apg =
      (const unsigned short*)Ain + (size_t)(mt * 128 + srow) * K + scb * 8;
  const int NT = K >> 5;
#pragma unroll
  for (int t0 = 0; t0 < 2; ++t0) {
    const int kt = t0 * 32;
    gload_lds16(apg + kt, Asb + t0 * 8192 + tid * 16);
    gload_lds16(apg + (size_t)64 * K + kt, Asb + t0 * 8192 + 4096 + tid * 16);
    gload_lds16(wpg + kt, Bsb + t0 * 8192 + tid * 16);
    gload_lds16(wpg + (size_t)64 * K + kt, Bsb + t0 * 8192 + 4096 + tid * 16);
  }
  int cur = 0;
  for (int t = 0; t < NT; ++t) {
    if (t + 1 < NT)
      asm volatile("s_waitcnt vmcnt(4)" ::: "memory");
    else
      asm volatile("s_waitcnt vmcnt(0)" ::: "memory");
    asm volatile("s_barrier" ::: "memory");
    bf16x8 af[4], bfr[4];
#pragma unroll
    for (int i = 0; i < 4; ++i)
      af[i] = *(const bf16x8*)(Asb + cur * 8192 + (wr * 64 + i * 16 + lm) * 64 +
                               ((l4 ^ kx) * 16));
#pragma unroll
    for (int j = 0; j < 4; ++j)
      bfr[j] = *(const bf16x8*)(Bsb + cur * 8192 + (wc * 64 + j * 16 + lm) * 64 +
                                ((l4 ^ kx) * 16));
#pragma unroll
    for (int i = 0; i < 4; ++i)
#pragma unroll
      for (int j = 0; j < 4; ++j)
        acc[i][j] = __builtin_amdgcn_mfma_f32_16x16x32_bf16(af[i], bfr[j], acc[i][j], 0, 0, 0);
    asm volatile("s_barrier" ::: "memory");
    if (t + 2 < NT) {
      const int kt = (t + 2) * 32;
      gload_lds16(apg + kt, Asb + cur * 8192 + tid * 16);
      gload_lds16(apg + (size_t)64 * K + kt, Asb + cur * 8192 + 4096 + tid * 16);
      gload_lds16(wpg + kt, Bsb + cur * 8192 + tid * 16);
      gload_lds16(wpg + (size_t)64 * K + kt, Bsb + cur * 8192 + 4096 + tid * 16);
    }
    cur ^= 1;
  }

  const int c0o = nt * 128 + wc * 64 + lm;
  float bb[4];
#pragma unroll
  for (int j = 0; j < 4; ++j) bb[j] = bias[c0o + j * 16];
  const int mslot = wr ? cs1 : cs0;  // this wave's 64-row output slot

  if (OUT_MODE < 2) {
#pragma unroll
    for (int i = 0; i < 4; ++i)
#pragma unroll
      for (int j = 0; j < 4; ++j)
#pragma unroll
        for (int p = 0; p < 4; ++p) {
          size_t grow = (size_t)mslot * 64 + (l4 * 4 + i * 16 + p);
          size_t idx = grow * N + (size_t)(c0o + j * 16);
          float v = acc[i][j][p] + bb[j];
          if (SC) v *= 0.125f;  // exact exponent shift; bf16(v/8) == bf16(v)/8
          if (OUT_MODE == 1)
            ((unsigned short*)Cout)[idx] = f2bf(v);
          else
            ((float*)Cout)[idx] = v;
        }
  } else {
    // V^T per-head tiles: vt[(slot*16+h)*4096 + d*64 + t], t = i*16+l4*4+p
    const int hh = (nt * 128 + wc * 64) / 64;
    unsigned short* vt = (unsigned short*)Cout;
    const size_t base = ((size_t)mslot * 16 + hh) * 4096;
#pragma unroll
    for (int j = 0; j < 4; ++j) {
      const int d = lm + j * 16;
#pragma unroll
      for (int i = 0; i < 4; ++i) {
        uint2 wv;
        wv.x = pack2(acc[i][j][0] + bb[j], acc[i][j][1] + bb[j]);
        wv.y = pack2(acc[i][j][2] + bb[j], acc[i][j][3] + bb[j]);
        *(uint2*)(vt + base + (size_t)d * 64 + i * 16 + l4 * 4) = wv;
      }
    }
  }
}

// ----------------------------- fused attention -----------------------------
// One block per (h, b); 8 waves, wave w owns q rows [16w,16w+16).
// Swapped-operand MFMAs so q = lane&15 everywhere; online softmax over r.
// LDS (48KB): kv_s[2][K,V] 32KB; pa_s 16KB; q/sa^T staging overlays.
// launch_bounds (512,4): PROVEN config (round-23's (512,6) squeezed VGPR
// 64->40 and spilled, FETCH 95->339MB -- do not raise min-waves here).
// Active-review compaction: reviews with mask==1 (when any mask==0 exists in
// row b) have pooled weight exactly 0.0f (expf(-1e30 - max) underflows) ->
// skipped entirely.  Bitmask is uniform per block (depends only on b).
__global__ __launch_bounds__(512, 4) void attn2(
    const unsigned short* __restrict__ qb, const unsigned short* __restrict__ kb,
    const unsigned short* __restrict__ vtg, const int* __restrict__ mask,
    const int* __restrict__ mask2, const float* __restrict__ sa_a,
    const float* __restrict__ sa_b, unsigned short* __restrict__ merged) {
  const int h = (int)blockIdx.x;
  const int b = (int)blockIdx.y;
  const int tid = (int)threadIdx.x;
  const int lane = tid & 63, wave = tid >> 6;
  const int lm = lane & 15, l4 = lane >> 4;
  const int sw = (lm & 7) << 4;

  __shared__ unsigned short kv_s[2][2][64 * 64];  // [buf][0=K [t][d], 1=V^T [d][t]]
  __shared__ unsigned short pa_s[8 * 16 * 64];    // wave-private P/att rows

  char* kvb0 = (char*)kv_s;          // buf stride 16384; V^T at +8192
  char* qreg = (char*)kv_s + 16384;  // q staging region = buf1 (dead after hoist)
  char* satb = (char*)pa_s;          // sa^T staging (dead after hoist)

  // ---- active-review bitmask (uniform across the block) ----
  unsigned am = 0u;
#pragma unroll
  for (int rr = 0; rr < 20; ++rr)
    am |= (mask[b * 20 + rr] == 0) ? (1u << rr) : 0u;
  // az (= some review has mask==0) => only those reviews survive; else all.
  const unsigned act = am ? am : 0xFFFFFu;

  // ---- stage Q into qreg (pre-swizzled source columns) ----
#pragma unroll
  for (int s = 0; s < 2; ++s) {
    int idx = s * 512 + tid, row = idx >> 3, blk = idx & 7;
    int cb = blk ^ (row & 7);
    gload_lds16(qb + (size_t)(b * 128 + row) * 1024 + h * 64 + cb * 8, qreg + idx * 16);
  }
  // ---- stage sa^T into satb: sat[jj][d] = sa_a[d][jj], swizzled ----
#pragma unroll
  for (int s = 0; s < 8; ++s) {
    int idx = s * 512 + tid, jj = idx & 63, d = idx >> 6;
    *(unsigned short*)(satb + jj * 128 + ((d * 2) ^ ((jj & 7) << 4))) =
        f2bf(sa_a[d * 64 + jj]);
  }
  // ---- stage first ACTIVE review K/V into buf0 ----
  const int srow = tid >> 3, sblk = tid & 7;
  const int scb = sblk ^ (srow & 7);
  int r = (int)__builtin_ctz(act);
  unsigned rem = act & (act - 1u);
  gload_lds16(kb + ((size_t)(b * 20 + r) * 64 + srow) * 1024 + h * 64 + scb * 8,
              kvb0 + tid * 16);
  gload_lds16(vtg + ((size_t)(b * 20 + r) * 16 + h) * 4096 + srow * 64 + scb * 8,
              kvb0 + 8192 + tid * 16);

  f32x4 sbv[4];
#pragma unroll
  for (int i = 0; i < 4; ++i) sbv[i] = *(const f32x4*)(sa_b + i * 16 + l4 * 4);

  __syncthreads();  // qreg, satb, buf0 all visible

  // ---- hoist Q B-fragments and sa^T A-fragments to registers ----
  const char* qrp = qreg + (wave * 16 + lm) * 128;
  bf16x8 qf[2];
  qf[0] = *(const bf16x8*)(qrp + ((l4 * 16) ^ sw));
  qf[1] = *(const bf16x8*)(qrp + ((64 + l4 * 16) ^ sw));
  bf16x8 sfr[2][4];
#pragma unroll
  for (int kk = 0; kk < 2; ++kk)
#pragma unroll
    for (int i = 0; i < 4; ++i)
      sfr[kk][i] = *(const bf16x8*)(satb + (i * 16 + lm) * 128 +
                                    ((kk * 64 + l4 * 16) ^ sw));
  asm volatile("s_waitcnt lgkmcnt(0)" ::: "memory");  // hoist reads retired
  __syncthreads();  // all waves done -> qreg/satb reusable as buf1 / P-rows

  char* pw = (char*)pa_s + wave * 2048 + lm * 128;  // wave-private row q=lm

  f32x4 zero4 = {0.f, 0.f, 0.f, 0.f};
  f32x4 Pacc[4];
#pragma unroll
  for (int i = 0; i < 4; ++i) Pacc[i] = zero4;
  float m_run = -3.0e38f, s_run = 0.0f;

  int it = 0;
  for (;;) {
    const int pb = it & 1;
    if (it) __syncthreads();  // buf[pb] staged; all waves done with buf[1-pb]
    const int nr = rem ? (int)__builtin_ctz(rem) : -1;
    if (nr >= 0) {  // stage next active review (flies under this one's compute)
      const int nbuf = pb ^ 1;
      gload_lds16(kb + ((size_t)(b * 20 + nr) * 64 + srow) * 1024 + h * 64 + scb * 8,
                  kvb0 + nbuf * 16384 + tid * 16);
      gload_lds16(vtg + ((size_t)(b * 20 + nr) * 16 + h) * 4096 + srow * 64 + scb * 8,
                  kvb0 + nbuf * 16384 + 8192 + tid * 16);
    }
    const char* kbse = kvb0 + pb * 16384;
    const char* vbse = kvb0 + pb * 16384 + 8192;

    // ---- S^T = mfma(K, Q): rows t, col q (q pre-scaled by 1/8) ----
    f32x4 sc[4];
#pragma unroll
    for (int i = 0; i < 4; ++i) sc[i] = zero4;
    __builtin_amdgcn_s_setprio(1);
#pragma unroll
    for (int kk = 0; kk < 2; ++kk) {
      bf16x8 kf[4];
#pragma unroll
      for (int i = 0; i < 4; ++i)
        kf[i] = *(const bf16x8*)(kbse + (i * 16 + lm) * 128 + ((kk * 64 + l4 * 16) ^ sw));
#pragma unroll
      for (int i = 0; i < 4; ++i)
        sc[i] = __builtin_amdgcn_mfma_f32_16x16x32_bf16(kf[i], qf[kk], sc[i], 0, 0, 0);
    }
    __builtin_amdgcn_s_setprio(0);

    // ---- token mask (scores already scaled) + softmax over t ----
    const int mbase = (b * 20 + r) * 64;
#pragma unroll
    for (int i = 0; i < 4; ++i) {
      int4 m2 = *(const int4*)(mask2 + mbase + i * 16 + l4 * 4);
      sc[i][0] = (m2.x == 0) ? -1e20f : sc[i][0];
      sc[i][1] = (m2.y == 0) ? -1e20f : sc[i][1];
      sc[i][2] = (m2.z == 0) ? -1e20f : sc[i][2];
      sc[i][3] = (m2.w == 0) ? -1e20f : sc[i][3];
    }
    float mx = sc[0][0];
#pragma unroll
    for (int i = 0; i < 4; ++i)
#pragma unroll
      for (int p = 0; p < 4; ++p) mx = fmaxf(mx, sc[i][p]);
    mx = fmaxf(mx, __shfl_xor(mx, 16));
    mx = fmaxf(mx, __shfl_xor(mx, 32));
    float sum = 0.f;
#pragma unroll
    for (int i = 0; i < 4; ++i)
#pragma unroll
      for (int p = 0; p < 4; ++p) {
        float e = __expf(sc[i][p] - mx);
        sc[i][p] = e;
        sum += e;
      }
    sum += __shfl_xor(sum, 16);
    sum += __shfl_xor(sum, 32);
    const float pinv = __builtin_amdgcn_rcpf(sum);

    // ---- P -> wave-private LDS [q][t], packed 8B swizzled writes ----
#pragma unroll
    for (int i = 0; i < 4; ++i) {
      uint2 wv;
      wv.x = pk2_rhu(sc[i][0] * pinv, sc[i][1] * pinv);
      wv.y = pk2_rhu(sc[i][2] * pinv, sc[i][3] * pinv);
      *(uint2*)(pw + ((i * 32 + l4 * 8) ^ sw)) = wv;
    }

    // ---- att^T = mfma(V^T, P): rows d, col q ----
    f32x4 av[4];
#pragma unroll
    for (int i = 0; i < 4; ++i) av[i] = zero4;
    __builtin_amdgcn_s_setprio(1);
#pragma unroll
    for (int kk = 0; kk < 2; ++kk) {
      bf16x8 pf = *(const bf16x8*)(pw + ((kk * 64 + l4 * 16) ^ sw));
      bf16x8 vf[4];
#pragma unroll
      for (int i = 0; i < 4; ++i)
        vf[i] = *(const bf16x8*)(vbse + (i * 16 + lm) * 128 + ((kk * 64 + l4 * 16) ^ sw));
#pragma unroll
      for (int i = 0; i < 4; ++i)
        av[i] = __builtin_amdgcn_mfma_f32_16x16x32_bf16(vf[i], pf, av[i], 0, 0, 0);
    }
    __builtin_amdgcn_s_setprio(0);

    // ---- att -> same wave-private LDS [q][d] (P already consumed) ----
#pragma unroll
    for (int i = 0; i < 4; ++i) {
      uint2 wv;
      wv.x = pk2_rhu(av[i][0], av[i][1]);
      wv.y = pk2_rhu(av[i][2], av[i][3]);
      *(uint2*)(pw + ((i * 32 + l4 * 8) ^ sw)) = wv;
    }

    // ---- e^T = mfma(sa^T, att): rows jj, col q ----
    f32x4 ep[4];
#pragma unroll
    for (int i = 0; i < 4; ++i) ep[i] = zero4;
    __builtin_amdgcn_s_setprio(1);
#pragma unroll
    for (int kk = 0; kk < 2; ++kk) {
      bf16x8 afr = *(const bf16x8*)(pw + ((kk * 64 + l4 * 16) ^ sw));
#pragma unroll
      for (int i = 0; i < 4; ++i)
        ep[i] = __builtin_amdgcn_mfma_f32_16x16x32_bf16(sfr[kk][i], afr, ep[i], 0, 0, 0);
    }
    __builtin_amdgcn_s_setprio(0);
    float a = 0.f;
#pragma unroll
    for (int i = 0; i < 4; ++i)
#pragma unroll
      for (int p = 0; p < 4; ++p) a += fast_tanh(ep[i][p]) * sbv[i][p];
    a += __shfl_xor(a, 16);
    a += __shfl_xor(a, 32);

    // ---- exact online softmax update over active reviews ----
    // All surviving reviews have add_mask == 0, so e_r = a directly.
    const float e_r = a;
    const float mnew = fmaxf(m_run, e_r);
    const float scl = __expf(m_run - mnew);
    const float w = __expf(e_r - mnew);
    s_run = s_run * scl + w;
#pragma unroll
    for (int i = 0; i < 4; ++i)
#pragma unroll
      for (int p = 0; p < 4; ++p) Pacc[i][p] = Pacc[i][p] * scl + w * av[i][p];
    m_run = mnew;

    if (nr < 0) break;
    r = nr;
    rem &= rem - 1u;
    ++it;
  }

  // ---- merged[b*128+q][h*64+d] = bf16(Pacc / s) ----
  const float inv_s = __builtin_amdgcn_rcpf(s_run);
  unsigned short* mrow = merged + (size_t)(b * 128 + wave * 16 + lm) * 1024 + h * 64;
#pragma unroll
  for (int i = 0; i < 4; ++i) {
    uint2 o;
    o.x = pk2_rhu(Pacc[i][0] * inv_s, Pacc[i][1] * inv_s);
    o.y = pk2_rhu(Pacc[i][2] * inv_s, Pacc[i][3] * inv_s);
    *(uint2*)(mrow + i * 16 + l4 * 4) = o;
  }
}

// ---------------------------------------------------------------------------
extern "C" void kernel_launch(void* const* d_in, const int* in_sizes, int n_in,
                              void* d_out, int out_size, void* d_ws, size_t ws_size,
                              hipStream_t stream) {
  (void)in_sizes; (void)n_in; (void)out_size; (void)ws_size;
  const float* query = (const float*)d_in[0];
  const float* key   = (const float*)d_in[1];
  const float* value = (const float*)d_in[2];
  const int*   mask  = (const int*)d_in[3];
  const int*   mask2 = (const int*)d_in[4];
  const float* Wq = (const float*)d_in[5];
  const float* bq = (const float*)d_in[6];
  const float* Wk = (const float*)d_in[7];
  const float* bk = (const float*)d_in[8];
  const float* Wv = (const float*)d_in[9];
  const float* bv = (const float*)d_in[10];
  const float* Wo = (const float*)d_in[11];
  const float* bo = (const float*)d_in[12];
  const float* sa_a = (const float*)d_in[13];
  const float* sa_b = (const float*)d_in[14];

  char* ws = (char*)d_ws;
  size_t off = 0;
  auto carve = [&](size_t bytes) -> char* {
    char* p = ws + off;
    off += (bytes + 255) & ~(size_t)255;
    return p;
  };
  unsigned short* wq_b = (unsigned short*)carve((size_t)1024 * 1024 * 2);
  unsigned short* wk_b = (unsigned short*)carve((size_t)1024 * 1024 * 2);
  unsigned short* wv_b = (unsigned short*)carve((size_t)1024 * 1024 * 2);
  unsigned short* wo_b = (unsigned short*)carve((size_t)1024 * 1024 * 2);
  unsigned short* q_b  = (unsigned short*)carve((size_t)4096 * 1024 * 2);
  unsigned short* k_b  = (unsigned short*)carve((size_t)40960 * 1024 * 2);
  unsigned short* vt_g = (unsigned short*)carve((size_t)40960 * 1024 * 2);
  unsigned short* mrg  = (unsigned short*)carve((size_t)4096 * 1024 * 2);
  int* cmp = (int*)carve(4096);
  // shared compacted-activation buffer (reused Q, K, V serially; same-stream
  // ordering guarantees each GEMM consumes act before the next cvt rewrites
  // it).  Total ws ~264MB = round-1 fat-path footprint (proven available).
  unsigned short* act = (unsigned short*)carve((size_t)40960 * 1024 * 2);

  cvt_w4<<<1024, 256, 0, stream>>>(Wq, Wk, Wv, Wo, wq_b, wk_b, wv_b, wo_b);
  compact_rv<<<1, 64, 0, stream>>>(mask, cmp);

  // Q projection: plain cvt -> proven bf16-A GEMM (x0.125 epilogue)
  cvt_bf16<<<1024, 256, 0, stream>>>(query, act, 4096 * 1024 / 8);
  gemm_bt<1, 1, 1, 0><<<dim3(32 * 8), 256, 0, stream>>>(act, wq_b, bq, q_b, 1024, 1024, 8, cmp);

  // K projection: compacted cvt -> proven bf16-A GEMM (dense A, slot C-write)
  cvt_act<<<2048, 256, 0, stream>>>(key, act, cmp);
  gemm_bt<1, 1, 0, 1><<<dim3(320 * 8), 256, 0, stream>>>(act, wk_b, bk, k_b, 1024, 1024, 8, cmp);

  // V projection: same act buffer (K-GEMM already consumed it)
  cvt_act<<<2048, 256, 0, stream>>>(value, act, cmp);
  gemm_bt<2, 1, 0, 1><<<dim3(320 * 8), 256, 0, stream>>>(act, wv_b, bv, vt_g, 1024, 1024, 8, cmp);

  attn2<<<dim3(16, 32), 512, 0, stream>>>(q_b, k_b, vt_g, mask, mask2, sa_a, sa_b, mrg);

  // out projection: A (mrg) is bf16 -> proven bf16-A path
  gemm_bt<0, 1, 0, 0><<<dim3(32 * 8), 256, 0, stream>>>(mrg, wo_b, bo, d_out, 1024, 1024, 8, cmp);
}

// Round 12
// 259.036 us; speedup vs baseline: 1.4032x; 1.0301x over previous
//
#include <hip/hip_runtime.h>
#include <stdint.h>

// ---------------------------------------------------------------------------
// FineReviewDecoderAttention: prep (weights cvt + Q cvt + active-review
// compaction, ONE kernel) -> q/k/v proj (bf16 MFMA GEMM, counted-vmcnt
// 2-buffer pipeline + proven T2 swizzle, chunked XCD swizzle for compacted
// grids; K/V fed by compacted cvt_act) -> fused attention -> out proj.
// B=32 Q=128 D=1024 H=16 d=64 R=20.
// Delta vs round 24 (passed, 266.8us = best): three safe levers:
//  (1) cvt_w4 + cvt_bf16(Q) + compact_rv merged into ONE prep kernel
//      (blocks 0-1023 weights, 1024-2047 Q-cvt, 2048 compact; block-uniform
//      branch; ballot confined to wave 0).  10 -> 8 dispatches.
//  (2) attn2 (VALU-bound: VALUBusy 49%, MfmaUtil 10%): pk2_rhu (~5 ops/pair)
//      -> v_cvt_pk_bf16_f32 (1 op, RNE -- proven bit-safe in round-16 GEMM
//      A-path, identical absmax) at P/att/merged write sites.
//  (3) mask2 int4 loads hoisted ABOVE the QK^T MFMA cluster so global-load
//      latency hides under MFMA instead of serializing the softmax chain.
// GEMM / cvt_act / sync structures untouched.
// ---------------------------------------------------------------------------

typedef __attribute__((ext_vector_type(8))) short bf16x8;
typedef __attribute__((ext_vector_type(4))) float f32x4;
typedef __attribute__((ext_vector_type(4))) unsigned int u32x4;
typedef __attribute__((address_space(1))) const unsigned int as1_t;
typedef __attribute__((address_space(3))) unsigned int as3_t;

#define DEVI static __device__ __forceinline__

DEVI unsigned short f2bf(float f) {  // RNE f32->bf16 (finite inputs)
  unsigned int u = __float_as_uint(f);
  u += 0x7fffu + ((u >> 16) & 1u);
  return (unsigned short)(u >> 16);
}
DEVI unsigned int pack2(float a, float b) {
  return (unsigned int)f2bf(a) | ((unsigned int)f2bf(b) << 16);
}
// HW packed f32->bf16 (RNE): a -> lo16, b -> hi16.  (round-16-proven)
DEVI unsigned int cvtpk(float a, float b) {
  unsigned int r;
  asm("v_cvt_pk_bf16_f32 %0, %1, %2" : "=v"(r) : "v"(a), "v"(b));
  return r;
}

DEVI void gload_lds16(const void* g, void* l) {
  __builtin_amdgcn_global_load_lds((as1_t*)g, (as3_t*)l, 16, 0, 0);
}

DEVI float fast_tanh(float x) {  // round-5-proven form
  float ax = fabsf(x);
  float e = __expf(2.0f * ax);
  float r = __builtin_fmaf(-2.0f, __builtin_amdgcn_rcpf(e + 1.0f), 1.0f);
  return copysignf(r, x);
}

// ------- prep: weights f32->bf16, Q f32->bf16, active-slot compaction ------
// blocks 0..1023: weight cvt (4 tensors, 262144 f32x4 units each)
// blocks 1024..2047: Q cvt (524288 8-elem units, 2 per thread)
// block 2048: compaction.  cmp[0]=count; cmp[1..cnt]=ascending active slots;
// cmp[1+cnt]=last active slot (pad for odd count).  active(s): if batch b
// has any mask==0 -> (mask[s]==0), else all active (attn2's bit-exact
// criterion, round-14).
__global__ __launch_bounds__(256) void prep(
    const float* __restrict__ w0, const float* __restrict__ w1,
    const float* __restrict__ w2, const float* __restrict__ w3,
    unsigned short* __restrict__ o0, unsigned short* __restrict__ o1,
    unsigned short* __restrict__ o2, unsigned short* __restrict__ o3,
    const float* __restrict__ qsrc, unsigned short* __restrict__ qdst,
    const int* __restrict__ mask, int* __restrict__ cmp) {
  const int bx = (int)blockIdx.x;
  const int tid = (int)threadIdx.x;
  if (bx < 1024) {
    const int i = bx * 256 + tid;  // < 262144 by construction
    f32x4 v;
    uint2 a;
    v = ((const f32x4*)w0)[i]; a.x = pack2(v[0], v[1]); a.y = pack2(v[2], v[3]);
    *(uint2*)(o0 + 4 * (size_t)i) = a;
    v = ((const f32x4*)w1)[i]; a.x = pack2(v[0], v[1]); a.y = pack2(v[2], v[3]);
    *(uint2*)(o1 + 4 * (size_t)i) = a;
    v = ((const f32x4*)w2)[i]; a.x = pack2(v[0], v[1]); a.y = pack2(v[2], v[3]);
    *(uint2*)(o2 + 4 * (size_t)i) = a;
    v = ((const f32x4*)w3)[i]; a.x = pack2(v[0], v[1]); a.y = pack2(v[2], v[3]);
    *(uint2*)(o3 + 4 * (size_t)i) = a;
  } else if (bx < 2048) {
    // Q: 524288 units of 8 f32; thread handles units i and i+262144.
    const int i = (bx - 1024) * 256 + tid;
#pragma unroll
    for (int h = 0; h < 2; ++h) {
      const int u = i + h * 262144;
      f32x4 a = ((const f32x4*)qsrc)[2 * u];
      f32x4 b = ((const f32x4*)qsrc)[2 * u + 1];
      u32x4 o = {pack2(a[0], a[1]), pack2(a[2], a[3]),
                 pack2(b[0], b[1]), pack2(b[2], b[3])};
      ((u32x4*)qdst)[u] = o;
    }
  } else {
    // compaction (wave 0 does the ballot scan; all threads hit the barrier)
    __shared__ int azs[32];
    if (tid < 32) {
      int z = 0;
#pragma unroll
      for (int r = 0; r < 20; ++r) z |= (mask[tid * 20 + r] == 0) ? 1 : 0;
      azs[tid] = z;
    }
    __syncthreads();
    if (tid < 64) {
      const int lane = tid;
      int base = 0;
      int lasts = 0;
      for (int it = 0; it < 10; ++it) {
        const int s = it * 64 + lane;
        const int bb = s / 20;
        const int actv = azs[bb] ? ((mask[s] == 0) ? 1 : 0) : 1;
        unsigned long long bal = __ballot(actv);
        const int off = (int)__popcll(bal & ((1ull << lane) - 1ull));
        if (actv) {
          cmp[1 + base + off] = s;
          lasts = s;
        }
        base += (int)__popcll(bal);
      }
#pragma unroll
      for (int d = 1; d < 64; d <<= 1) {
        int o = __shfl_xor(lasts, d);
        lasts = lasts > o ? lasts : o;
      }
      if (lane == 0) {
        cmp[0] = base;
        cmp[1 + base] = lasts;  // pad for odd count
      }
    }
  }
}

// --------------- compacted activation f32 -> bf16 (active slots) -----------
// dst is DENSE: compact position s holds slot cmp[1+s].  Converts
// round_up_even(cnt) slots so the odd-count pad tile reads valid data.
// Unit = 8 elements; slot = 64 rows x 1024 cols = 8192 units.
__global__ void cvt_act(const float* __restrict__ src,
                        unsigned short* __restrict__ dst,
                        const int* __restrict__ cmp) {
  const int cnt = cmp[0];
  const int n = ((cnt + 1) & ~1) * 8192;
  const int stride = (int)(gridDim.x * blockDim.x);
  for (int u = (int)(blockIdx.x * blockDim.x + threadIdx.x); u < n; u += stride) {
    const int s = u >> 13;
    const int e = u & 8191;
    const size_t so = (size_t)cmp[1 + s] * 65536 + (size_t)e * 8;
    f32x4 a = *(const f32x4*)(src + so);
    f32x4 b = *(const f32x4*)(src + so + 4);
    u32x4 o = {pack2(a[0], a[1]), pack2(a[2], a[3]),
               pack2(b[0], b[1]), pack2(b[2], b[3])};
    *(u32x4*)(dst + (size_t)u * 8) = o;
  }
}

// ---------------- C[m,n] = sum_k A[m,k]*W[n,k] + bias[n] -------------------
// OUT_MODE: 0 = f32 row-major, 1 = bf16 row-major, 2 = bf16 per-head V^T.
// A is bf16 (round-12-proven gload_lds path, 0-conflict tiles).  SC=1:
// epilogue x0.125.  CMP=1: A is DENSE-compacted (indexed by mt); C-writes
// go to absolute slots cs0/cs1 from cmp; active-aware chunked XCD swizzle;
// blocks beyond the active count exit early (uniform).
template <int OUT_MODE, int ADT, int SC, int CMP>
__global__ __launch_bounds__(256, 4) void gemm_bt(
    const void* __restrict__ Ain, const unsigned short* __restrict__ W,
    const float* __restrict__ bias, void* __restrict__ Cout, int N, int K, int nnt,
    const int* __restrict__ cmp) {
  __shared__ __align__(16) char smem[32768];
  char* Asb = smem;
  char* Bsb = smem + 16384;
  const int tid = (int)threadIdx.x;
  const int lane = tid & 63, wave = tid >> 6;
  const int lm = lane & 15, l4 = lane >> 4;
  const int nb = (int)gridDim.x;
  const int bx = (int)blockIdx.x;
  const int wr = wave >> 1, wc = wave & 1;

  // ---- tile mapping + output slot mapping (64-row slots: cs0, cs1) ----
  int mt, nt, cs0, cs1;
  if (CMP) {
    const int cnt = cmp[0];
    const int tiles = (cnt + 1) >> 1;   // ceil(cnt/2)
    if (bx >= tiles * 8) return;        // uniform exit before any barrier
    // chunked XCD swizzle (round-20-proven): XCD (= bx&7) owns a contiguous
    // lg chunk -> nt cycles within one mt, mt slices per XCD.
    const int lg = (bx & 7) * tiles + (bx >> 3);
    mt = lg / nnt;
    nt = lg % nnt;
    cs0 = cmp[1 + 2 * mt];
    cs1 = cmp[2 + 2 * mt];
  } else {
    const int lg = (bx & 7) * (nb >> 3) + (bx >> 3);
    mt = lg / nnt;
    nt = lg % nnt;
    cs0 = 2 * mt;
    cs1 = 2 * mt + 1;
  }

  f32x4 zero4 = {0.f, 0.f, 0.f, 0.f};
  f32x4 acc[4][4];
#pragma unroll
  for (int i = 0; i < 4; ++i)
#pragma unroll
    for (int j = 0; j < 4; ++j) acc[i][j] = zero4;

  // ---- staging mapping: row = tid>>2, 16B chunk = tid&3.
  // T2 swizzle: chunk (row,blk) lives at slot (row, blk ^ ((row>>1)&3)).
  // Linear LDS dest (tid*16) => pre-swizzle the GLOBAL column: scb.
  const int srow = tid >> 2, sblk = tid & 3;
  const int scb = sblk ^ ((srow >> 1) & 3);
  const unsigned short* wpg = W + (size_t)(nt * 128 + srow) * K + scb * 8;
  // fragment-read XOR key (proven): kx = (lm>>1)&3.
  const int kx = (lm >> 1) & 3;

  // ---- bf16-A path (round-12-proven): counted-vmcnt, swizzled tiles.
  // CMP=1: A is dense-compacted -> index by mt directly.
  const unsigned short* apg =
      (const unsigned short*)Ain + (size_t)(mt * 128 + srow) * K + scb * 8;
  const int NT = K >> 5;
#pragma unroll
  for (int t0 = 0; t0 < 2; ++t0) {
    const int kt = t0 * 32;
    gload_lds16(apg + kt, Asb + t0 * 8192 + tid * 16);
    gload_lds16(apg + (size_t)64 * K + kt, Asb + t0 * 8192 + 4096 + tid * 16);
    gload_lds16(wpg + kt, Bsb + t0 * 8192 + tid * 16);
    gload_lds16(wpg + (size_t)64 * K + kt, Bsb + t0 * 8192 + 4096 + tid * 16);
  }
  int cur = 0;
  for (int t = 0; t < NT; ++t) {
    if (t + 1 < NT)
      asm volatile("s_waitcnt vmcnt(4)" ::: "memory");
    else
      asm volatile("s_waitcnt vmcnt(0)" ::: "memory");
    asm volatile("s_barrier" ::: "memory");
    bf16x8 af[4], bfr[4];
#pragma unroll
    for (int i = 0; i < 4; ++i)
      af[i] = *(const bf16x8*)(Asb + cur * 8192 + (wr * 64 + i * 16 + lm) * 64 +
                               ((l4 ^ kx) * 16));
#pragma unroll
    for (int j = 0; j < 4; ++j)
      bfr[j] = *(const bf16x8*)(Bsb + cur * 8192 + (wc * 64 + j * 16 + lm) * 64 +
                                ((l4 ^ kx) * 16));
#pragma unroll
    for (int i = 0; i < 4; ++i)
#pragma unroll
      for (int j = 0; j < 4; ++j)
        acc[i][j] = __builtin_amdgcn_mfma_f32_16x16x32_bf16(af[i], bfr[j], acc[i][j], 0, 0, 0);
    asm volatile("s_barrier" ::: "memory");
    if (t + 2 < NT) {
      const int kt = (t + 2) * 32;
      gload_lds16(apg + kt, Asb + cur * 8192 + tid * 16);
      gload_lds16(apg + (size_t)64 * K + kt, Asb + cur * 8192 + 4096 + tid * 16);
      gload_lds16(wpg + kt, Bsb + cur * 8192 + tid * 16);
      gload_lds16(wpg + (size_t)64 * K + kt, Bsb + cur * 8192 + 4096 + tid * 16);
    }
    cur ^= 1;
  }

  const int c0o = nt * 128 + wc * 64 + lm;
  float bb[4];
#pragma unroll
  for (int j = 0; j < 4; ++j) bb[j] = bias[c0o + j * 16];
  const int mslot = wr ? cs1 : cs0;  // this wave's 64-row output slot

  if (OUT_MODE < 2) {
#pragma unroll
    for (int i = 0; i < 4; ++i)
#pragma unroll
      for (int j = 0; j < 4; ++j)
#pragma unroll
        for (int p = 0; p < 4; ++p) {
          size_t grow = (size_t)mslot * 64 + (l4 * 4 + i * 16 + p);
          size_t idx = grow * N + (size_t)(c0o + j * 16);
          float v = acc[i][j][p] + bb[j];
          if (SC) v *= 0.125f;  // exact exponent shift; bf16(v/8) == bf16(v)/8
          if (OUT_MODE == 1)
            ((unsigned short*)Cout)[idx] = f2bf(v);
          else
            ((float*)Cout)[idx] = v;
        }
  } else {
    // V^T per-head tiles: vt[(slot*16+h)*4096 + d*64 + t], t = i*16+l4*4+p
    const int hh = (nt * 128 + wc * 64) / 64;
    unsigned short* vt = (unsigned short*)Cout;
    const size_t base = ((size_t)mslot * 16 + hh) * 4096;
#pragma unroll
    for (int j = 0; j < 4; ++j) {
      const int d = lm + j * 16;
#pragma unroll
      for (int i = 0; i < 4; ++i) {
        uint2 wv;
        wv.x = pack2(acc[i][j][0] + bb[j], acc[i][j][1] + bb[j]);
        wv.y = pack2(acc[i][j][2] + bb[j], acc[i][j][3] + bb[j]);
        *(uint2*)(vt + base + (size_t)d * 64 + i * 16 + l4 * 4) = wv;
      }
    }
  }
}

// ----------------------------- fused attention -----------------------------
// One block per (h, b); 8 waves, wave w owns q rows [16w,16w+16).
// Swapped-operand MFMAs so q = lane&15 everywhere; online softmax over r.
// LDS (48KB): kv_s[2][K,V] 32KB; pa_s 16KB; q/sa^T staging overlays.
// launch_bounds (512,4): PROVEN config (round-23's (512,6) squeezed VGPR
// 64->40 and spilled, FETCH 95->339MB -- do not raise min-waves here).
// VALU cuts (this round): cvtpk (1-op RNE pack) at P/att/merged writes;
// mask2 loads hoisted above the QK^T cluster (latency under MFMA).
// Active-review compaction: reviews with mask==1 (when any mask==0 exists in
// row b) have pooled weight exactly 0.0f (expf(-1e30 - max) underflows) ->
// skipped entirely.  Bitmask is uniform per block (depends only on b).
__global__ __launch_bounds__(512, 4) void attn2(
    const unsigned short* __restrict__ qb, const unsigned short* __restrict__ kb,
    const unsigned short* __restrict__ vtg, const int* __restrict__ mask,
    const int* __restrict__ mask2, const float* __restrict__ sa_a,
    const float* __restrict__ sa_b, unsigned short* __restrict__ merged) {
  const int h = (int)blockIdx.x;
  const int b = (int)blockIdx.y;
  const int tid = (int)threadIdx.x;
  const int lane = tid & 63, wave = tid >> 6;
  const int lm = lane & 15, l4 = lane >> 4;
  const int sw = (lm & 7) << 4;

  __shared__ unsigned short kv_s[2][2][64 * 64];  // [buf][0=K [t][d], 1=V^T [d][t]]
  __shared__ unsigned short pa_s[8 * 16 * 64];    // wave-private P/att rows

  char* kvb0 = (char*)kv_s;          // buf stride 16384; V^T at +8192
  char* qreg = (char*)kv_s + 16384;  // q staging region = buf1 (dead after hoist)
  char* satb = (char*)pa_s;          // sa^T staging (dead after hoist)

  // ---- active-review bitmask (uniform across the block) ----
  unsigned am = 0u;
#pragma unroll
  for (int rr = 0; rr < 20; ++rr)
    am |= (mask[b * 20 + rr] == 0) ? (1u << rr) : 0u;
  // az (= some review has mask==0) => only those reviews survive; else all.
  const unsigned act = am ? am : 0xFFFFFu;

  // ---- stage Q into qreg (pre-swizzled source columns) ----
#pragma unroll
  for (int s = 0; s < 2; ++s) {
    int idx = s * 512 + tid, row = idx >> 3, blk = idx & 7;
    int cb = blk ^ (row & 7);
    gload_lds16(qb + (size_t)(b * 128 + row) * 1024 + h * 64 + cb * 8, qreg + idx * 16);
  }
  // ---- stage sa^T into satb: sat[jj][d] = sa_a[d][jj], swizzled ----
#pragma unroll
  for (int s = 0; s < 8; ++s) {
    int idx = s * 512 + tid, jj = idx & 63, d = idx >> 6;
    *(unsigned short*)(satb + jj * 128 + ((d * 2) ^ ((jj & 7) << 4))) =
        f2bf(sa_a[d * 64 + jj]);
  }
  // ---- stage first ACTIVE review K/V into buf0 ----
  const int srow = tid >> 3, sblk = tid & 7;
  const int scb = sblk ^ (srow & 7);
  int r = (int)__builtin_ctz(act);
  unsigned rem = act & (act - 1u);
  gload_lds16(kb + ((size_t)(b * 20 + r) * 64 + srow) * 1024 + h * 64 + scb * 8,
              kvb0 + tid * 16);
  gload_lds16(vtg + ((size_t)(b * 20 + r) * 16 + h) * 4096 + srow * 64 + scb * 8,
              kvb0 + 8192 + tid * 16);

  f32x4 sbv[4];
#pragma unroll
  for (int i = 0; i < 4; ++i) sbv[i] = *(const f32x4*)(sa_b + i * 16 + l4 * 4);

  __syncthreads();  // qreg, satb, buf0 all visible

  // ---- hoist Q B-fragments and sa^T A-fragments to registers ----
  const char* qrp = qreg + (wave * 16 + lm) * 128;
  bf16x8 qf[2];
  qf[0] = *(const bf16x8*)(qrp + ((l4 * 16) ^ sw));
  qf[1] = *(const bf16x8*)(qrp + ((64 + l4 * 16) ^ sw));
  bf16x8 sfr[2][4];
#pragma unroll
  for (int kk = 0; kk < 2; ++kk)
#pragma unroll
    for (int i = 0; i < 4; ++i)
      sfr[kk][i] = *(const bf16x8*)(satb + (i * 16 + lm) * 128 +
                                    ((kk * 64 + l4 * 16) ^ sw));
  asm volatile("s_waitcnt lgkmcnt(0)" ::: "memory");  // hoist reads retired
  __syncthreads();  // all waves done -> qreg/satb reusable as buf1 / P-rows

  char* pw = (char*)pa_s + wave * 2048 + lm * 128;  // wave-private row q=lm

  f32x4 zero4 = {0.f, 0.f, 0.f, 0.f};
  f32x4 Pacc[4];
#pragma unroll
  for (int i = 0; i < 4; ++i) Pacc[i] = zero4;
  float m_run = -3.0e38f, s_run = 0.0f;

  int it = 0;
  for (;;) {
    const int pb = it & 1;
    if (it) __syncthreads();  // buf[pb] staged; all waves done with buf[1-pb]
    const int nr = rem ? (int)__builtin_ctz(rem) : -1;
    if (nr >= 0) {  // stage next active review (flies under this one's compute)
      const int nbuf = pb ^ 1;
      gload_lds16(kb + ((size_t)(b * 20 + nr) * 64 + srow) * 1024 + h * 64 + scb * 8,
                  kvb0 + nbuf * 16384 + tid * 16);
      gload_lds16(vtg + ((size_t)(b * 20 + nr) * 16 + h) * 4096 + srow * 64 + scb * 8,
                  kvb0 + nbuf * 16384 + 8192 + tid * 16);
    }
    const char* kbse = kvb0 + pb * 16384;
    const char* vbse = kvb0 + pb * 16384 + 8192;

    // ---- mask2 loads issued BEFORE the MFMA cluster (latency hides) ----
    const int mbase = (b * 20 + r) * 64;
    int4 m2v[4];
#pragma unroll
    for (int i = 0; i < 4; ++i)
      m2v[i] = *(const int4*)(mask2 + mbase + i * 16 + l4 * 4);

    // ---- S^T = mfma(K, Q): rows t, col q (q pre-scaled by 1/8) ----
    f32x4 sc[4];
#pragma unroll
    for (int i = 0; i < 4; ++i) sc[i] = zero4;
    __builtin_amdgcn_s_setprio(1);
#pragma unroll
    for (int kk = 0; kk < 2; ++kk) {
      bf16x8 kf[4];
#pragma unroll
      for (int i = 0; i < 4; ++i)
        kf[i] = *(const bf16x8*)(kbse + (i * 16 + lm) * 128 + ((kk * 64 + l4 * 16) ^ sw));
#pragma unroll
      for (int i = 0; i < 4; ++i)
        sc[i] = __builtin_amdgcn_mfma_f32_16x16x32_bf16(kf[i], qf[kk], sc[i], 0, 0, 0);
    }
    __builtin_amdgcn_s_setprio(0);

    // ---- token mask (scores already scaled) + softmax over t ----
#pragma unroll
    for (int i = 0; i < 4; ++i) {
      sc[i][0] = (m2v[i].x == 0) ? -1e20f : sc[i][0];
      sc[i][1] = (m2v[i].y == 0) ? -1e20f : sc[i][1];
      sc[i][2] = (m2v[i].z == 0) ? -1e20f : sc[i][2];
      sc[i][3] = (m2v[i].w == 0) ? -1e20f : sc[i][3];
    }
    float mx = sc[0][0];
#pragma unroll
    for (int i = 0; i < 4; ++i)
#pragma unroll
      for (int p = 0; p < 4; ++p) mx = fmaxf(mx, sc[i][p]);
    mx = fmaxf(mx, __shfl_xor(mx, 16));
    mx = fmaxf(mx, __shfl_xor(mx, 32));
    float sum = 0.f;
#pragma unroll
    for (int i = 0; i < 4; ++i)
#pragma unroll
      for (int p = 0; p < 4; ++p) {
        float e = __expf(sc[i][p] - mx);
        sc[i][p] = e;
        sum += e;
      }
    sum += __shfl_xor(sum, 16);
    sum += __shfl_xor(sum, 32);
    const float pinv = __builtin_amdgcn_rcpf(sum);

    // ---- P -> wave-private LDS [q][t], packed 8B swizzled writes ----
#pragma unroll
    for (int i = 0; i < 4; ++i) {
      uint2 wv;
      wv.x = cvtpk(sc[i][0] * pinv, sc[i][1] * pinv);
      wv.y = cvtpk(sc[i][2] * pinv, sc[i][3] * pinv);
      *(uint2*)(pw + ((i * 32 + l4 * 8) ^ sw)) = wv;
    }

    // ---- att^T = mfma(V^T, P): rows d, col q ----
    f32x4 av[4];
#pragma unroll
    for (int i = 0; i < 4; ++i) av[i] = zero4;
    __builtin_amdgcn_s_setprio(1);
#pragma unroll
    for (int kk = 0; kk < 2; ++kk) {
      bf16x8 pf = *(const bf16x8*)(pw + ((kk * 64 + l4 * 16) ^ sw));
      bf16x8 vf[4];
#pragma unroll
      for (int i = 0; i < 4; ++i)
        vf[i] = *(const bf16x8*)(vbse + (i * 16 + lm) * 128 + ((kk * 64 + l4 * 16) ^ sw));
#pragma unroll
      for (int i = 0; i < 4; ++i)
        av[i] = __builtin_amdgcn_mfma_f32_16x16x32_bf16(vf[i], pf, av[i], 0, 0, 0);
    }
    __builtin_amdgcn_s_setprio(0);

    // ---- att -> same wave-private LDS [q][d] (P already consumed) ----
#pragma unroll
    for (int i = 0; i < 4; ++i) {
      uint2 wv;
      wv.x = cvtpk(av[i][0], av[i][1]);
      wv.y = cvtpk(av[i][2], av[i][3]);
      *(uint2*)(pw + ((i * 32 + l4 * 8) ^ sw)) = wv;
    }

    // ---- e^T = mfma(sa^T, att): rows jj, col q ----
    f32x4 ep[4];
#pragma unroll
    for (int i = 0; i < 4; ++i) ep[i] = zero4;
    __builtin_amdgcn_s_setprio(1);
#pragma unroll
    for (int kk = 0; kk < 2; ++kk) {
      bf16x8 afr = *(const bf16x8*)(pw + ((kk * 64 + l4 * 16) ^ sw));
#pragma unroll
      for (int i = 0; i < 4; ++i)
        ep[i] = __builtin_amdgcn_mfma_f32_16x16x32_bf16(sfr[kk][i], afr, ep[i], 0, 0, 0);
    }
    __builtin_amdgcn_s_setprio(0);
    float a = 0.f;
#pragma unroll
    for (int i = 0; i < 4; ++i)
#pragma unroll
      for (int p = 0; p < 4; ++p) a += fast_tanh(ep[i][p]) * sbv[i][p];
    a += __shfl_xor(a, 16);
    a += __shfl_xor(a, 32);

    // ---- exact online softmax update over active reviews ----
    // All surviving reviews have add_mask == 0, so e_r = a directly.
    const float e_r = a;
    const float mnew = fmaxf(m_run, e_r);
    const float scl = __expf(m_run - mnew);
    const float w = __expf(e_r - mnew);
    s_run = s_run * scl + w;
#pragma unroll
    for (int i = 0; i < 4; ++i)
#pragma unroll
      for (int p = 0; p < 4; ++p) Pacc[i][p] = Pacc[i][p] * scl + w * av[i][p];
    m_run = mnew;

    if (nr < 0) break;
    r = nr;
    rem &= rem - 1u;
    ++it;
  }

  // ---- merged[b*128+q][h*64+d] = bf16(Pacc / s) ----
  const float inv_s = __builtin_amdgcn_rcpf(s_run);
  unsigned short* mrow = merged + (size_t)(b * 128 + wave * 16 + lm) * 1024 + h * 64;
#pragma unroll
  for (int i = 0; i < 4; ++i) {
    uint2 o;
    o.x = cvtpk(Pacc[i][0] * inv_s, Pacc[i][1] * inv_s);
    o.y = cvtpk(Pacc[i][2] * inv_s, Pacc[i][3] * inv_s);
    *(uint2*)(mrow + i * 16 + l4 * 4) = o;
  }
}

// ---------------------------------------------------------------------------
extern "C" void kernel_launch(void* const* d_in, const int* in_sizes, int n_in,
                              void* d_out, int out_size, void* d_ws, size_t ws_size,
                              hipStream_t stream) {
  (void)in_sizes; (void)n_in; (void)out_size; (void)ws_size;
  const float* query = (const float*)d_in[0];
  const float* key   = (const float*)d_in[1];
  const float* value = (const float*)d_in[2];
  const int*   mask  = (const int*)d_in[3];
  const int*   mask2 = (const int*)d_in[4];
  const float* Wq = (const float*)d_in[5];
  const float* bq = (const float*)d_in[6];
  const float* Wk = (const float*)d_in[7];
  const float* bk = (const float*)d_in[8];
  const float* Wv = (const float*)d_in[9];
  const float* bv = (const float*)d_in[10];
  const float* Wo = (const float*)d_in[11];
  const float* bo = (const float*)d_in[12];
  const float* sa_a = (const float*)d_in[13];
  const float* sa_b = (const float*)d_in[14];

  char* ws = (char*)d_ws;
  size_t off = 0;
  auto carve = [&](size_t bytes) -> char* {
    char* p = ws + off;
    off += (bytes + 255) & ~(size_t)255;
    return p;
  };
  unsigned short* wq_b = (unsigned short*)carve((size_t)1024 * 1024 * 2);
  unsigned short* wk_b = (unsigned short*)carve((size_t)1024 * 1024 * 2);
  unsigned short* wv_b = (unsigned short*)carve((size_t)1024 * 1024 * 2);
  unsigned short* wo_b = (unsigned short*)carve((size_t)1024 * 1024 * 2);
  unsigned short* q_b  = (unsigned short*)carve((size_t)4096 * 1024 * 2);
  unsigned short* k_b  = (unsigned short*)carve((size_t)40960 * 1024 * 2);
  unsigned short* vt_g = (unsigned short*)carve((size_t)40960 * 1024 * 2);
  unsigned short* mrg  = (unsigned short*)carve((size_t)4096 * 1024 * 2);
  int* cmp = (int*)carve(4096);
  // shared compacted-activation buffer (reused Q, K, V serially; same-stream
  // ordering guarantees each GEMM consumes act before the next cvt rewrites
  // it).  Total ws ~264MB = round-1 fat-path footprint (proven available).
  unsigned short* act = (unsigned short*)carve((size_t)40960 * 1024 * 2);

  // prep: weights cvt + Q cvt + active-slot compaction in one dispatch
  prep<<<2049, 256, 0, stream>>>(Wq, Wk, Wv, Wo, wq_b, wk_b, wv_b, wo_b,
                                 query, act, mask, cmp);

  // Q projection: proven bf16-A GEMM (x0.125 epilogue)
  gemm_bt<1, 1, 1, 0><<<dim3(32 * 8), 256, 0, stream>>>(act, wq_b, bq, q_b, 1024, 1024, 8, cmp);

  // K projection: compacted cvt -> proven bf16-A GEMM (dense A, slot C-write)
  cvt_act<<<2048, 256, 0, stream>>>(key, act, cmp);
  gemm_bt<1, 1, 0, 1><<<dim3(320 * 8), 256, 0, stream>>>(act, wk_b, bk, k_b, 1024, 1024, 8, cmp);

  // V projection: same act buffer (K-GEMM already consumed it)
  cvt_act<<<2048, 256, 0, stream>>>(value, act, cmp);
  gemm_bt<2, 1, 0, 1><<<dim3(320 * 8), 256, 0, stream>>>(act, wv_b, bv, vt_g, 1024, 1024, 8, cmp);

  attn2<<<dim3(16, 32), 512, 0, stream>>>(q_b, k_b, vt_g, mask, mask2, sa_a, sa_b, mrg);

  // out projection: A (mrg) is bf16 -> proven bf16-A path
  gemm_bt<0, 1, 0, 0><<<dim3(32 * 8), 256, 0, stream>>>(mrg, wo_b, bo, d_out, 1024, 1024, 8, cmp);
}

// Round 13
// 254.997 us; speedup vs baseline: 1.4254x; 1.0158x over previous
//
#include <hip/hip_runtime.h>
#include <stdint.h>

// ---------------------------------------------------------------------------
// FineReviewDecoderAttention: prep (weights cvt + Q cvt + compaction + K
// sparse-cvt, ONE kernel) -> gemm_qk (Q-proj + K-proj, ONE dispatch) ->
// V sparse-cvt -> V-proj -> fused attention -> out proj.
// B=32 Q=128 D=1024 H=16 d=64 R=20.
// Delta vs round 25 (passed, 259.0us = best): serialization cuts only, all
// inner loops byte-identical:
//  (1) K-cvt folded into prep as extra blocks.  To avoid intra-dispatch
//      dependency on cmp, cvt writes SPARSE/ABSOLUTE (dst idx = src idx;
//      inactive slots skipped via per-block self-computed 640-entry active
//      bitmap, 672B LDS).  Same converted bytes as the compacted version.
//  (2) K/V GEMM A-addressing: dense-mt -> slot-indirect (cs0*64 / cs1*64 +
//      srow), the round-18..20-proven form; for CMP=0 cs0/cs1 = 2mt/2mt+1
//      makes it bit-identical to the dense path -> one unified body.
//  (3) Q-gemm merged into the K-gemm dispatch (gemm_qk: bx<256 -> Q body,
//      else K body; GEMM loop extracted into a templated device function).
//      XCD alignment preserved (256 % 8 == 0).
// Dispatches 8 -> 6.  attn2 / out-proj untouched.
// ---------------------------------------------------------------------------

typedef __attribute__((ext_vector_type(8))) short bf16x8;
typedef __attribute__((ext_vector_type(4))) float f32x4;
typedef __attribute__((ext_vector_type(4))) unsigned int u32x4;
typedef __attribute__((address_space(1))) const unsigned int as1_t;
typedef __attribute__((address_space(3))) unsigned int as3_t;

#define DEVI static __device__ __forceinline__

DEVI unsigned short f2bf(float f) {  // RNE f32->bf16 (finite inputs)
  unsigned int u = __float_as_uint(f);
  u += 0x7fffu + ((u >> 16) & 1u);
  return (unsigned short)(u >> 16);
}
DEVI unsigned int pack2(float a, float b) {
  return (unsigned int)f2bf(a) | ((unsigned int)f2bf(b) << 16);
}
// HW packed f32->bf16 (RNE): a -> lo16, b -> hi16.  (round-16-proven)
DEVI unsigned int cvtpk(float a, float b) {
  unsigned int r;
  asm("v_cvt_pk_bf16_f32 %0, %1, %2" : "=v"(r) : "v"(a), "v"(b));
  return r;
}

DEVI void gload_lds16(const void* g, void* l) {
  __builtin_amdgcn_global_load_lds((as1_t*)g, (as3_t*)l, 16, 0, 0);
}

DEVI float fast_tanh(float x) {  // round-5-proven form
  float ax = fabsf(x);
  float e = __expf(2.0f * ax);
  float r = __builtin_fmaf(-2.0f, __builtin_amdgcn_rcpf(e + 1.0f), 1.0f);
  return copysignf(r, x);
}

// ---- sparse activation cvt helper: convert active slots, absolute layout.
// actb: 640-entry active bitmap (LDS).  Unit = 8 elements; dst idx = src idx.
DEVI void cvt_sparse_body(const float* __restrict__ src,
                          unsigned short* __restrict__ dst,
                          const unsigned char* actb, int gid, int stride) {
  for (int u = gid; u < 640 * 8192; u += stride) {
    const int s = u >> 13;
    if (!actb[s]) continue;
    f32x4 a = *(const f32x4*)(src + (size_t)u * 8);
    f32x4 b = *(const f32x4*)(src + (size_t)u * 8 + 4);
    u32x4 o = {pack2(a[0], a[1]), pack2(a[2], a[3]),
               pack2(b[0], b[1]), pack2(b[2], b[3])};
    *(u32x4*)(dst + (size_t)u * 8) = o;
  }
}

// build the 640-entry active bitmap in LDS (azs: per-batch any-zero)
DEVI void build_actb(const int* __restrict__ mask, unsigned char* actb,
                     int* azs, int tid) {
  if (tid < 32) {
    int z = 0;
#pragma unroll
    for (int r = 0; r < 20; ++r) z |= (mask[tid * 20 + r] == 0) ? 1 : 0;
    azs[tid] = z;
  }
  __syncthreads();
  for (int s = tid; s < 640; s += 256)
    actb[s] = azs[s / 20] ? ((mask[s] == 0) ? 1 : 0) : 1;
  __syncthreads();
}

// ------- prep: weights f32->bf16, Q f32->bf16, compaction, K sparse-cvt ----
// blocks 0..1023: weight cvt; 1024..2047: Q cvt; 2048: compaction;
// 2049..4096: K sparse cvt (self-computed active bitmap, no cmp dep).
__global__ __launch_bounds__(256) void prep(
    const float* __restrict__ w0, const float* __restrict__ w1,
    const float* __restrict__ w2, const float* __restrict__ w3,
    unsigned short* __restrict__ o0, unsigned short* __restrict__ o1,
    unsigned short* __restrict__ o2, unsigned short* __restrict__ o3,
    const float* __restrict__ qsrc, unsigned short* __restrict__ qdst,
    const float* __restrict__ ksrc, unsigned short* __restrict__ kdst,
    const int* __restrict__ mask, int* __restrict__ cmp) {
  const int bx = (int)blockIdx.x;
  const int tid = (int)threadIdx.x;
  if (bx < 1024) {
    const int i = bx * 256 + tid;  // < 262144 by construction
    f32x4 v;
    uint2 a;
    v = ((const f32x4*)w0)[i]; a.x = pack2(v[0], v[1]); a.y = pack2(v[2], v[3]);
    *(uint2*)(o0 + 4 * (size_t)i) = a;
    v = ((const f32x4*)w1)[i]; a.x = pack2(v[0], v[1]); a.y = pack2(v[2], v[3]);
    *(uint2*)(o1 + 4 * (size_t)i) = a;
    v = ((const f32x4*)w2)[i]; a.x = pack2(v[0], v[1]); a.y = pack2(v[2], v[3]);
    *(uint2*)(o2 + 4 * (size_t)i) = a;
    v = ((const f32x4*)w3)[i]; a.x = pack2(v[0], v[1]); a.y = pack2(v[2], v[3]);
    *(uint2*)(o3 + 4 * (size_t)i) = a;
  } else if (bx < 2048) {
    // Q: 524288 units of 8 f32; thread handles units i and i+262144.
    const int i = (bx - 1024) * 256 + tid;
#pragma unroll
    for (int h = 0; h < 2; ++h) {
      const int u = i + h * 262144;
      f32x4 a = ((const f32x4*)qsrc)[2 * u];
      f32x4 b = ((const f32x4*)qsrc)[2 * u + 1];
      u32x4 o = {pack2(a[0], a[1]), pack2(a[2], a[3]),
                 pack2(b[0], b[1]), pack2(b[2], b[3])};
      ((u32x4*)qdst)[u] = o;
    }
  } else if (bx == 2048) {
    // compaction: cmp[0]=count; cmp[1..cnt]=ascending active slots;
    // cmp[1+cnt]=last active slot (pad for odd count).
    __shared__ int azs[32];
    if (tid < 32) {
      int z = 0;
#pragma unroll
      for (int r = 0; r < 20; ++r) z |= (mask[tid * 20 + r] == 0) ? 1 : 0;
      azs[tid] = z;
    }
    __syncthreads();
    if (tid < 64) {
      const int lane = tid;
      int base = 0;
      int lasts = 0;
      for (int it = 0; it < 10; ++it) {
        const int s = it * 64 + lane;
        const int bb = s / 20;
        const int actv = azs[bb] ? ((mask[s] == 0) ? 1 : 0) : 1;
        unsigned long long bal = __ballot(actv);
        const int off = (int)__popcll(bal & ((1ull << lane) - 1ull));
        if (actv) {
          cmp[1 + base + off] = s;
          lasts = s;
        }
        base += (int)__popcll(bal);
      }
#pragma unroll
      for (int d = 1; d < 64; d <<= 1) {
        int o = __shfl_xor(lasts, d);
        lasts = lasts > o ? lasts : o;
      }
      if (lane == 0) {
        cmp[0] = base;
        cmp[1 + base] = lasts;  // pad for odd count
      }
    }
  } else {
    // K sparse cvt (2048 blocks), self-computed active bitmap
    __shared__ unsigned char actb[640];
    __shared__ int azs[32];
    build_actb(mask, actb, azs, tid);
    cvt_sparse_body(ksrc, kdst, actb, (bx - 2049) * 256 + tid, 2048 * 256);
  }
}

// --------------- standalone sparse activation cvt (V) ----------------------
__global__ __launch_bounds__(256) void cvt_sp(const float* __restrict__ src,
                                              unsigned short* __restrict__ dst,
                                              const int* __restrict__ mask) {
  __shared__ unsigned char actb[640];
  __shared__ int azs[32];
  const int tid = (int)threadIdx.x;
  build_actb(mask, actb, azs, tid);
  cvt_sparse_body(src, dst, actb, (int)(blockIdx.x * 256) + tid,
                  (int)(gridDim.x * 256));
}

// ---------------- C[m,n] = sum_k A[m,k]*W[n,k] + bias[n] -------------------
// OUT_MODE: 0 = f32 row-major, 1 = bf16 row-major, 2 = bf16 per-head V^T.
// A is bf16, SPARSE/absolute slot layout; rows indirect via cs0/cs1 (for
// CMP=0, cs0/cs1 = 2mt/2mt+1 == dense).  Proven 0-conflict tiles,
// counted-vmcnt pipeline.  SC=1: epilogue x0.125.  CMP=1: chunked XCD
// swizzle + early exit on active count.
template <int OUT_MODE, int SC, int CMP>
DEVI void gemm_body(const void* __restrict__ Ain,
                    const unsigned short* __restrict__ W,
                    const float* __restrict__ bias, void* __restrict__ Cout,
                    int N, int K, int nnt, int nb, int bx,
                    const int* __restrict__ cmp, char* smem) {
  char* Asb = smem;
  char* Bsb = smem + 16384;
  const int tid = (int)threadIdx.x;
  const int lane = tid & 63, wave = tid >> 6;
  const int lm = lane & 15, l4 = lane >> 4;
  const int wr = wave >> 1, wc = wave & 1;

  // ---- tile mapping + slot mapping (64-row slots: cs0, cs1) ----
  int mt, nt, cs0, cs1;
  if (CMP) {
    const int cnt = cmp[0];
    const int tiles = (cnt + 1) >> 1;   // ceil(cnt/2)
    if (bx >= tiles * 8) return;        // uniform exit before any barrier
    const int lg = (bx & 7) * tiles + (bx >> 3);
    mt = lg / nnt;
    nt = lg % nnt;
    cs0 = cmp[1 + 2 * mt];
    cs1 = cmp[2 + 2 * mt];
  } else {
    const int lg = (bx & 7) * (nb >> 3) + (bx >> 3);
    mt = lg / nnt;
    nt = lg % nnt;
    cs0 = 2 * mt;
    cs1 = 2 * mt + 1;
  }

  f32x4 zero4 = {0.f, 0.f, 0.f, 0.f};
  f32x4 acc[4][4];
#pragma unroll
  for (int i = 0; i < 4; ++i)
#pragma unroll
    for (int j = 0; j < 4; ++j) acc[i][j] = zero4;

  // ---- staging mapping: row = tid>>2, 16B chunk = tid&3; T2 swizzle ----
  const int srow = tid >> 2, sblk = tid & 3;
  const int scb = sblk ^ ((srow >> 1) & 3);
  const unsigned short* wpg = W + (size_t)(nt * 128 + srow) * K + scb * 8;
  const int kx = (lm >> 1) & 3;

  // slot-indirect A bases (CMP=0: == dense mt*128 / mt*128+64 rows)
  const unsigned short* apg0 =
      (const unsigned short*)Ain + ((size_t)cs0 * 64 + srow) * K + scb * 8;
  const unsigned short* apg1 =
      (const unsigned short*)Ain + ((size_t)cs1 * 64 + srow) * K + scb * 8;
  const int NT = K >> 5;
#pragma unroll
  for (int t0 = 0; t0 < 2; ++t0) {
    const int kt = t0 * 32;
    gload_lds16(apg0 + kt, Asb + t0 * 8192 + tid * 16);
    gload_lds16(apg1 + kt, Asb + t0 * 8192 + 4096 + tid * 16);
    gload_lds16(wpg + kt, Bsb + t0 * 8192 + tid * 16);
    gload_lds16(wpg + (size_t)64 * K + kt, Bsb + t0 * 8192 + 4096 + tid * 16);
  }
  int cur = 0;
  for (int t = 0; t < NT; ++t) {
    if (t + 1 < NT)
      asm volatile("s_waitcnt vmcnt(4)" ::: "memory");
    else
      asm volatile("s_waitcnt vmcnt(0)" ::: "memory");
    asm volatile("s_barrier" ::: "memory");
    bf16x8 af[4], bfr[4];
#pragma unroll
    for (int i = 0; i < 4; ++i)
      af[i] = *(const bf16x8*)(Asb + cur * 8192 + (wr * 64 + i * 16 + lm) * 64 +
                               ((l4 ^ kx) * 16));
#pragma unroll
    for (int j = 0; j < 4; ++j)
      bfr[j] = *(const bf16x8*)(Bsb + cur * 8192 + (wc * 64 + j * 16 + lm) * 64 +
                                ((l4 ^ kx) * 16));
#pragma unroll
    for (int i = 0; i < 4; ++i)
#pragma unroll
      for (int j = 0; j < 4; ++j)
        acc[i][j] = __builtin_amdgcn_mfma_f32_16x16x32_bf16(af[i], bfr[j], acc[i][j], 0, 0, 0);
    asm volatile("s_barrier" ::: "memory");
    if (t + 2 < NT) {
      const int kt = (t + 2) * 32;
      gload_lds16(apg0 + kt, Asb + cur * 8192 + tid * 16);
      gload_lds16(apg1 + kt, Asb + cur * 8192 + 4096 + tid * 16);
      gload_lds16(wpg + kt, Bsb + cur * 8192 + tid * 16);
      gload_lds16(wpg + (size_t)64 * K + kt, Bsb + cur * 8192 + 4096 + tid * 16);
    }
    cur ^= 1;
  }

  const int c0o = nt * 128 + wc * 64 + lm;
  float bb[4];
#pragma unroll
  for (int j = 0; j < 4; ++j) bb[j] = bias[c0o + j * 16];
  const int mslot = wr ? cs1 : cs0;  // this wave's 64-row output slot

  if (OUT_MODE < 2) {
#pragma unroll
    for (int i = 0; i < 4; ++i)
#pragma unroll
      for (int j = 0; j < 4; ++j)
#pragma unroll
        for (int p = 0; p < 4; ++p) {
          size_t grow = (size_t)mslot * 64 + (l4 * 4 + i * 16 + p);
          size_t idx = grow * N + (size_t)(c0o + j * 16);
          float v = acc[i][j][p] + bb[j];
          if (SC) v *= 0.125f;  // exact exponent shift
          if (OUT_MODE == 1)
            ((unsigned short*)Cout)[idx] = f2bf(v);
          else
            ((float*)Cout)[idx] = v;
        }
  } else {
    // V^T per-head tiles: vt[(slot*16+h)*4096 + d*64 + t], t = i*16+l4*4+p
    const int hh = (nt * 128 + wc * 64) / 64;
    unsigned short* vt = (unsigned short*)Cout;
    const size_t base = ((size_t)mslot * 16 + hh) * 4096;
#pragma unroll
    for (int j = 0; j < 4; ++j) {
      const int d = lm + j * 16;
#pragma unroll
      for (int i = 0; i < 4; ++i) {
        uint2 wv;
        wv.x = pack2(acc[i][j][0] + bb[j], acc[i][j][1] + bb[j]);
        wv.y = pack2(acc[i][j][2] + bb[j], acc[i][j][3] + bb[j]);
        *(uint2*)(vt + base + (size_t)d * 64 + i * 16 + l4 * 4) = wv;
      }
    }
  }
}

// ---- merged Q+K projection: bx<256 -> Q (CMP=0,SC=1); else K (CMP=1) ----
__global__ __launch_bounds__(256, 4) void gemm_qk(
    const unsigned short* __restrict__ aq, const unsigned short* __restrict__ wq,
    const float* __restrict__ bq, unsigned short* __restrict__ qout,
    const unsigned short* __restrict__ ak, const unsigned short* __restrict__ wk,
    const float* __restrict__ bk, unsigned short* __restrict__ kout,
    const int* __restrict__ cmp) {
  __shared__ __align__(16) char smem[32768];
  const int bx = (int)blockIdx.x;
  if (bx < 256)
    gemm_body<1, 1, 0>(aq, wq, bq, qout, 1024, 1024, 8, 256, bx, cmp, smem);
  else
    gemm_body<1, 0, 1>(ak, wk, bk, kout, 1024, 1024, 8, 2560, bx - 256, cmp, smem);
}

// ---- V projection (CMP=1, V^T output) ----
__global__ __launch_bounds__(256, 4) void gemm_v(
    const unsigned short* __restrict__ av, const unsigned short* __restrict__ wv,
    const float* __restrict__ bv, unsigned short* __restrict__ vout,
    const int* __restrict__ cmp) {
  __shared__ __align__(16) char smem[32768];
  gemm_body<2, 0, 1>(av, wv, bv, vout, 1024, 1024, 8, 2560, (int)blockIdx.x, cmp, smem);
}

// ---- out projection (CMP=0, f32 output) ----
__global__ __launch_bounds__(256, 4) void gemm_out(
    const unsigned short* __restrict__ am, const unsigned short* __restrict__ wo,
    const float* __restrict__ bo, float* __restrict__ oout,
    const int* __restrict__ cmp) {
  __shared__ __align__(16) char smem[32768];
  gemm_body<0, 0, 0>(am, wo, bo, oout, 1024, 1024, 8, 256, (int)blockIdx.x, cmp, smem);
}

// ----------------------------- fused attention -----------------------------
// One block per (h, b); 8 waves, wave w owns q rows [16w,16w+16).
// Swapped-operand MFMAs so q = lane&15 everywhere; online softmax over r.
// LDS (48KB): kv_s[2][K,V] 32KB; pa_s 16KB; q/sa^T staging overlays.
// launch_bounds (512,4): PROVEN config (do not raise min-waves: round-23's
// (512,6) squeezed VGPR 64->40 and spilled).
// Active-review compaction: reviews with mask==1 (when any mask==0 exists in
// row b) have pooled weight exactly 0.0f (expf(-1e30 - max) underflows) ->
// skipped entirely.  Bitmask is uniform per block (depends only on b).
__global__ __launch_bounds__(512, 4) void attn2(
    const unsigned short* __restrict__ qb, const unsigned short* __restrict__ kb,
    const unsigned short* __restrict__ vtg, const int* __restrict__ mask,
    const int* __restrict__ mask2, const float* __restrict__ sa_a,
    const float* __restrict__ sa_b, unsigned short* __restrict__ merged) {
  const int h = (int)blockIdx.x;
  const int b = (int)blockIdx.y;
  const int tid = (int)threadIdx.x;
  const int lane = tid & 63, wave = tid >> 6;
  const int lm = lane & 15, l4 = lane >> 4;
  const int sw = (lm & 7) << 4;

  __shared__ unsigned short kv_s[2][2][64 * 64];  // [buf][0=K [t][d], 1=V^T [d][t]]
  __shared__ unsigned short pa_s[8 * 16 * 64];    // wave-private P/att rows

  char* kvb0 = (char*)kv_s;          // buf stride 16384; V^T at +8192
  char* qreg = (char*)kv_s + 16384;  // q staging region = buf1 (dead after hoist)
  char* satb = (char*)pa_s;          // sa^T staging (dead after hoist)

  // ---- active-review bitmask (uniform across the block) ----
  unsigned am = 0u;
#pragma unroll
  for (int rr = 0; rr < 20; ++rr)
    am |= (mask[b * 20 + rr] == 0) ? (1u << rr) : 0u;
  const unsigned act = am ? am : 0xFFFFFu;

  // ---- stage Q into qreg (pre-swizzled source columns) ----
#pragma unroll
  for (int s = 0; s < 2; ++s) {
    int idx = s * 512 + tid, row = idx >> 3, blk = idx & 7;
    int cb = blk ^ (row & 7);
    gload_lds16(qb + (size_t)(b * 128 + row) * 1024 + h * 64 + cb * 8, qreg + idx * 16);
  }
  // ---- stage sa^T into satb: sat[jj][d] = sa_a[d][jj], swizzled ----
#pragma unroll
  for (int s = 0; s < 8; ++s) {
    int idx = s * 512 + tid, jj = idx & 63, d = idx >> 6;
    *(unsigned short*)(satb + jj * 128 + ((d * 2) ^ ((jj & 7) << 4))) =
        f2bf(sa_a[d * 64 + jj]);
  }
  // ---- stage first ACTIVE review K/V into buf0 ----
  const int srow = tid >> 3, sblk = tid & 7;
  const int scb = sblk ^ (srow & 7);
  int r = (int)__builtin_ctz(act);
  unsigned rem = act & (act - 1u);
  gload_lds16(kb + ((size_t)(b * 20 + r) * 64 + srow) * 1024 + h * 64 + scb * 8,
              kvb0 + tid * 16);
  gload_lds16(vtg + ((size_t)(b * 20 + r) * 16 + h) * 4096 + srow * 64 + scb * 8,
              kvb0 + 8192 + tid * 16);

  f32x4 sbv[4];
#pragma unroll
  for (int i = 0; i < 4; ++i) sbv[i] = *(const f32x4*)(sa_b + i * 16 + l4 * 4);

  __syncthreads();  // qreg, satb, buf0 all visible

  // ---- hoist Q B-fragments and sa^T A-fragments to registers ----
  const char* qrp = qreg + (wave * 16 + lm) * 128;
  bf16x8 qf[2];
  qf[0] = *(const bf16x8*)(qrp + ((l4 * 16) ^ sw));
  qf[1] = *(const bf16x8*)(qrp + ((64 + l4 * 16) ^ sw));
  bf16x8 sfr[2][4];
#pragma unroll
  for (int kk = 0; kk < 2; ++kk)
#pragma unroll
    for (int i = 0; i < 4; ++i)
      sfr[kk][i] = *(const bf16x8*)(satb + (i * 16 + lm) * 128 +
                                    ((kk * 64 + l4 * 16) ^ sw));
  asm volatile("s_waitcnt lgkmcnt(0)" ::: "memory");  // hoist reads retired
  __syncthreads();  // all waves done -> qreg/satb reusable as buf1 / P-rows

  char* pw = (char*)pa_s + wave * 2048 + lm * 128;  // wave-private row q=lm

  f32x4 zero4 = {0.f, 0.f, 0.f, 0.f};
  f32x4 Pacc[4];
#pragma unroll
  for (int i = 0; i < 4; ++i) Pacc[i] = zero4;
  float m_run = -3.0e38f, s_run = 0.0f;

  int it = 0;
  for (;;) {
    const int pb = it & 1;
    if (it) __syncthreads();  // buf[pb] staged; all waves done with buf[1-pb]
    const int nr = rem ? (int)__builtin_ctz(rem) : -1;
    if (nr >= 0) {  // stage next active review (flies under this one's compute)
      const int nbuf = pb ^ 1;
      gload_lds16(kb + ((size_t)(b * 20 + nr) * 64 + srow) * 1024 + h * 64 + scb * 8,
                  kvb0 + nbuf * 16384 + tid * 16);
      gload_lds16(vtg + ((size_t)(b * 20 + nr) * 16 + h) * 4096 + srow * 64 + scb * 8,
                  kvb0 + nbuf * 16384 + 8192 + tid * 16);
    }
    const char* kbse = kvb0 + pb * 16384;
    const char* vbse = kvb0 + pb * 16384 + 8192;

    // ---- mask2 loads issued BEFORE the MFMA cluster (latency hides) ----
    const int mbase = (b * 20 + r) * 64;
    int4 m2v[4];
#pragma unroll
    for (int i = 0; i < 4; ++i)
      m2v[i] = *(const int4*)(mask2 + mbase + i * 16 + l4 * 4);

    // ---- S^T = mfma(K, Q): rows t, col q (q pre-scaled by 1/8) ----
    f32x4 sc[4];
#pragma unroll
    for (int i = 0; i < 4; ++i) sc[i] = zero4;
    __builtin_amdgcn_s_setprio(1);
#pragma unroll
    for (int kk = 0; kk < 2; ++kk) {
      bf16x8 kf[4];
#pragma unroll
      for (int i = 0; i < 4; ++i)
        kf[i] = *(const bf16x8*)(kbse + (i * 16 + lm) * 128 + ((kk * 64 + l4 * 16) ^ sw));
#pragma unroll
      for (int i = 0; i < 4; ++i)
        sc[i] = __builtin_amdgcn_mfma_f32_16x16x32_bf16(kf[i], qf[kk], sc[i], 0, 0, 0);
    }
    __builtin_amdgcn_s_setprio(0);

    // ---- token mask (scores already scaled) + softmax over t ----
#pragma unroll
    for (int i = 0; i < 4; ++i) {
      sc[i][0] = (m2v[i].x == 0) ? -1e20f : sc[i][0];
      sc[i][1] = (m2v[i].y == 0) ? -1e20f : sc[i][1];
      sc[i][2] = (m2v[i].z == 0) ? -1e20f : sc[i][2];
      sc[i][3] = (m2v[i].w == 0) ? -1e20f : sc[i][3];
    }
    float mx = sc[0][0];
#pragma unroll
    for (int i = 0; i < 4; ++i)
#pragma unroll
      for (int p = 0; p < 4; ++p) mx = fmaxf(mx, sc[i][p]);
    mx = fmaxf(mx, __shfl_xor(mx, 16));
    mx = fmaxf(mx, __shfl_xor(mx, 32));
    float sum = 0.f;
#pragma unroll
    for (int i = 0; i < 4; ++i)
#pragma unroll
      for (int p = 0; p < 4; ++p) {
        float e = __expf(sc[i][p] - mx);
        sc[i][p] = e;
        sum += e;
      }
    sum += __shfl_xor(sum, 16);
    sum += __shfl_xor(sum, 32);
    const float pinv = __builtin_amdgcn_rcpf(sum);

    // ---- P -> wave-private LDS [q][t], packed 8B swizzled writes ----
#pragma unroll
    for (int i = 0; i < 4; ++i) {
      uint2 wv;
      wv.x = cvtpk(sc[i][0] * pinv, sc[i][1] * pinv);
      wv.y = cvtpk(sc[i][2] * pinv, sc[i][3] * pinv);
      *(uint2*)(pw + ((i * 32 + l4 * 8) ^ sw)) = wv;
    }

    // ---- att^T = mfma(V^T, P): rows d, col q ----
    f32x4 av[4];
#pragma unroll
    for (int i = 0; i < 4; ++i) av[i] = zero4;
    __builtin_amdgcn_s_setprio(1);
#pragma unroll
    for (int kk = 0; kk < 2; ++kk) {
      bf16x8 pf = *(const bf16x8*)(pw + ((kk * 64 + l4 * 16) ^ sw));
      bf16x8 vf[4];
#pragma unroll
      for (int i = 0; i < 4; ++i)
        vf[i] = *(const bf16x8*)(vbse + (i * 16 + lm) * 128 + ((kk * 64 + l4 * 16) ^ sw));
#pragma unroll
      for (int i = 0; i < 4; ++i)
        av[i] = __builtin_amdgcn_mfma_f32_16x16x32_bf16(vf[i], pf, av[i], 0, 0, 0);
    }
    __builtin_amdgcn_s_setprio(0);

    // ---- att -> same wave-private LDS [q][d] (P already consumed) ----
#pragma unroll
    for (int i = 0; i < 4; ++i) {
      uint2 wv;
      wv.x = cvtpk(av[i][0], av[i][1]);
      wv.y = cvtpk(av[i][2], av[i][3]);
      *(uint2*)(pw + ((i * 32 + l4 * 8) ^ sw)) = wv;
    }

    // ---- e^T = mfma(sa^T, att): rows jj, col q ----
    f32x4 ep[4];
#pragma unroll
    for (int i = 0; i < 4; ++i) ep[i] = zero4;
    __builtin_amdgcn_s_setprio(1);
#pragma unroll
    for (int kk = 0; kk < 2; ++kk) {
      bf16x8 afr = *(const bf16x8*)(pw + ((kk * 64 + l4 * 16) ^ sw));
#pragma unroll
      for (int i = 0; i < 4; ++i)
        ep[i] = __builtin_amdgcn_mfma_f32_16x16x32_bf16(sfr[kk][i], afr, ep[i], 0, 0, 0);
    }
    __builtin_amdgcn_s_setprio(0);
    float a = 0.f;
#pragma unroll
    for (int i = 0; i < 4; ++i)
#pragma unroll
      for (int p = 0; p < 4; ++p) a += fast_tanh(ep[i][p]) * sbv[i][p];
    a += __shfl_xor(a, 16);
    a += __shfl_xor(a, 32);

    // ---- exact online softmax update over active reviews ----
    const float e_r = a;
    const float mnew = fmaxf(m_run, e_r);
    const float scl = __expf(m_run - mnew);
    const float w = __expf(e_r - mnew);
    s_run = s_run * scl + w;
#pragma unroll
    for (int i = 0; i < 4; ++i)
#pragma unroll
      for (int p = 0; p < 4; ++p) Pacc[i][p] = Pacc[i][p] * scl + w * av[i][p];
    m_run = mnew;

    if (nr < 0) break;
    r = nr;
    rem &= rem - 1u;
    ++it;
  }

  // ---- merged[b*128+q][h*64+d] = bf16(Pacc / s) ----
  const float inv_s = __builtin_amdgcn_rcpf(s_run);
  unsigned short* mrow = merged + (size_t)(b * 128 + wave * 16 + lm) * 1024 + h * 64;
#pragma unroll
  for (int i = 0; i < 4; ++i) {
    uint2 o;
    o.x = cvtpk(Pacc[i][0] * inv_s, Pacc[i][1] * inv_s);
    o.y = cvtpk(Pacc[i][2] * inv_s, Pacc[i][3] * inv_s);
    *(uint2*)(mrow + i * 16 + l4 * 4) = o;
  }
}

// ---------------------------------------------------------------------------
extern "C" void kernel_launch(void* const* d_in, const int* in_sizes, int n_in,
                              void* d_out, int out_size, void* d_ws, size_t ws_size,
                              hipStream_t stream) {
  (void)in_sizes; (void)n_in; (void)out_size; (void)ws_size;
  const float* query = (const float*)d_in[0];
  const float* key   = (const float*)d_in[1];
  const float* value = (const float*)d_in[2];
  const int*   mask  = (const int*)d_in[3];
  const int*   mask2 = (const int*)d_in[4];
  const float* Wq = (const float*)d_in[5];
  const float* bq = (const float*)d_in[6];
  const float* Wk = (const float*)d_in[7];
  const float* bk = (const float*)d_in[8];
  const float* Wv = (const float*)d_in[9];
  const float* bv = (const float*)d_in[10];
  const float* Wo = (const float*)d_in[11];
  const float* bo = (const float*)d_in[12];
  const float* sa_a = (const float*)d_in[13];
  const float* sa_b = (const float*)d_in[14];

  char* ws = (char*)d_ws;
  size_t off = 0;
  auto carve = [&](size_t bytes) -> char* {
    char* p = ws + off;
    off += (bytes + 255) & ~(size_t)255;
    return p;
  };
  unsigned short* wq_b = (unsigned short*)carve((size_t)1024 * 1024 * 2);
  unsigned short* wk_b = (unsigned short*)carve((size_t)1024 * 1024 * 2);
  unsigned short* wv_b = (unsigned short*)carve((size_t)1024 * 1024 * 2);
  unsigned short* wo_b = (unsigned short*)carve((size_t)1024 * 1024 * 2);
  unsigned short* q_b  = (unsigned short*)carve((size_t)4096 * 1024 * 2);
  unsigned short* k_b  = (unsigned short*)carve((size_t)40960 * 1024 * 2);
  unsigned short* vt_g = (unsigned short*)carve((size_t)40960 * 1024 * 2);
  unsigned short* mrg  = (unsigned short*)carve((size_t)4096 * 1024 * 2);
  int* cmp = (int*)carve(4096);
  // shared sparse-activation buffer (reused K then V; same-stream ordering)
  unsigned short* act = (unsigned short*)carve((size_t)40960 * 1024 * 2);
  unsigned short* act_q = (unsigned short*)carve((size_t)4096 * 1024 * 2);

  // prep: weights cvt + Q cvt + compaction + K sparse-cvt, one dispatch
  prep<<<4097, 256, 0, stream>>>(Wq, Wk, Wv, Wo, wq_b, wk_b, wv_b, wo_b,
                                 query, act_q, key, act, mask, cmp);

  // Q + K projections in one dispatch (Q: 256 blocks; K: up to 2560)
  gemm_qk<<<256 + 2560, 256, 0, stream>>>(act_q, wq_b, bq, q_b,
                                          act, wk_b, bk, k_b, cmp);

  // V: sparse cvt (self-computed bitmap) -> projection
  cvt_sp<<<2048, 256, 0, stream>>>(value, act, mask);
  gemm_v<<<2560, 256, 0, stream>>>(act, wv_b, bv, vt_g, cmp);

  attn2<<<dim3(16, 32), 512, 0, stream>>>(q_b, k_b, vt_g, mask, mask2, sa_a, sa_b, mrg);

  gemm_out<<<256, 256, 0, stream>>>(mrg, wo_b, bo, (float*)d_out, cmp);
}

// Round 14
// 253.562 us; speedup vs baseline: 1.4335x; 1.0057x over previous
//
#include <hip/hip_runtime.h>
#include <stdint.h>

// ---------------------------------------------------------------------------
// FineReviewDecoderAttention: prep (weights cvt + Q cvt + compaction + K
// sparse-cvt) -> gemm_qkv (Q-proj + K-proj + V sparse-cvt, ONE dispatch,
// ws-guarded) -> V-proj -> fused attention -> out proj.
// B=32 Q=128 D=1024 H=16 d=64 R=20.
// Delta vs round 26 (passed, 255.0us = best): V sparse-cvt (~20us, fully
// serial between gemm_qk and gemm_v, independent of both) folded into the
// Q+K GEMM dispatch as a third block range (gemm blocks FIRST so K-gemm's
// critical path is not delayed; cvt blocks fill the retirement tail).  The
// GEMM dispatch is compute/latency-bound (HBM ~13%) so the streaming cvt
// rides along nearly free.  Needs act(K) + act_v(V) live simultaneously
// (+80MB ws) -> GUARDED: if ws_size is insufficient, exact round-26 serial
// path (gemm_qk + cvt_sp) runs instead.  All GEMM bodies / prep / attn2 /
// out-proj byte-identical to round 26.
// ---------------------------------------------------------------------------

typedef __attribute__((ext_vector_type(8))) short bf16x8;
typedef __attribute__((ext_vector_type(4))) float f32x4;
typedef __attribute__((ext_vector_type(4))) unsigned int u32x4;
typedef __attribute__((address_space(1))) const unsigned int as1_t;
typedef __attribute__((address_space(3))) unsigned int as3_t;

#define DEVI static __device__ __forceinline__

DEVI unsigned short f2bf(float f) {  // RNE f32->bf16 (finite inputs)
  unsigned int u = __float_as_uint(f);
  u += 0x7fffu + ((u >> 16) & 1u);
  return (unsigned short)(u >> 16);
}
DEVI unsigned int pack2(float a, float b) {
  return (unsigned int)f2bf(a) | ((unsigned int)f2bf(b) << 16);
}
// HW packed f32->bf16 (RNE): a -> lo16, b -> hi16.  (round-16-proven)
DEVI unsigned int cvtpk(float a, float b) {
  unsigned int r;
  asm("v_cvt_pk_bf16_f32 %0, %1, %2" : "=v"(r) : "v"(a), "v"(b));
  return r;
}

DEVI void gload_lds16(const void* g, void* l) {
  __builtin_amdgcn_global_load_lds((as1_t*)g, (as3_t*)l, 16, 0, 0);
}

DEVI float fast_tanh(float x) {  // round-5-proven form
  float ax = fabsf(x);
  float e = __expf(2.0f * ax);
  float r = __builtin_fmaf(-2.0f, __builtin_amdgcn_rcpf(e + 1.0f), 1.0f);
  return copysignf(r, x);
}

// ---- sparse activation cvt helper: convert active slots, absolute layout.
// actb: 640-entry active bitmap (LDS).  Unit = 8 elements; dst idx = src idx.
DEVI void cvt_sparse_body(const float* __restrict__ src,
                          unsigned short* __restrict__ dst,
                          const unsigned char* actb, int gid, int stride) {
  for (int u = gid; u < 640 * 8192; u += stride) {
    const int s = u >> 13;
    if (!actb[s]) continue;
    f32x4 a = *(const f32x4*)(src + (size_t)u * 8);
    f32x4 b = *(const f32x4*)(src + (size_t)u * 8 + 4);
    u32x4 o = {pack2(a[0], a[1]), pack2(a[2], a[3]),
               pack2(b[0], b[1]), pack2(b[2], b[3])};
    *(u32x4*)(dst + (size_t)u * 8) = o;
  }
}

// build the 640-entry active bitmap in LDS (azs: per-batch any-zero)
DEVI void build_actb(const int* __restrict__ mask, unsigned char* actb,
                     int* azs, int tid) {
  if (tid < 32) {
    int z = 0;
#pragma unroll
    for (int r = 0; r < 20; ++r) z |= (mask[tid * 20 + r] == 0) ? 1 : 0;
    azs[tid] = z;
  }
  __syncthreads();
  for (int s = tid; s < 640; s += 256)
    actb[s] = azs[s / 20] ? ((mask[s] == 0) ? 1 : 0) : 1;
  __syncthreads();
}

// ------- prep: weights f32->bf16, Q f32->bf16, compaction, K sparse-cvt ----
// blocks 0..1023: weight cvt; 1024..2047: Q cvt; 2048: compaction;
// 2049..4096: K sparse cvt (self-computed active bitmap, no cmp dep).
__global__ __launch_bounds__(256) void prep(
    const float* __restrict__ w0, const float* __restrict__ w1,
    const float* __restrict__ w2, const float* __restrict__ w3,
    unsigned short* __restrict__ o0, unsigned short* __restrict__ o1,
    unsigned short* __restrict__ o2, unsigned short* __restrict__ o3,
    const float* __restrict__ qsrc, unsigned short* __restrict__ qdst,
    const float* __restrict__ ksrc, unsigned short* __restrict__ kdst,
    const int* __restrict__ mask, int* __restrict__ cmp) {
  const int bx = (int)blockIdx.x;
  const int tid = (int)threadIdx.x;
  if (bx < 1024) {
    const int i = bx * 256 + tid;  // < 262144 by construction
    f32x4 v;
    uint2 a;
    v = ((const f32x4*)w0)[i]; a.x = pack2(v[0], v[1]); a.y = pack2(v[2], v[3]);
    *(uint2*)(o0 + 4 * (size_t)i) = a;
    v = ((const f32x4*)w1)[i]; a.x = pack2(v[0], v[1]); a.y = pack2(v[2], v[3]);
    *(uint2*)(o1 + 4 * (size_t)i) = a;
    v = ((const f32x4*)w2)[i]; a.x = pack2(v[0], v[1]); a.y = pack2(v[2], v[3]);
    *(uint2*)(o2 + 4 * (size_t)i) = a;
    v = ((const f32x4*)w3)[i]; a.x = pack2(v[0], v[1]); a.y = pack2(v[2], v[3]);
    *(uint2*)(o3 + 4 * (size_t)i) = a;
  } else if (bx < 2048) {
    // Q: 524288 units of 8 f32; thread handles units i and i+262144.
    const int i = (bx - 1024) * 256 + tid;
#pragma unroll
    for (int h = 0; h < 2; ++h) {
      const int u = i + h * 262144;
      f32x4 a = ((const f32x4*)qsrc)[2 * u];
      f32x4 b = ((const f32x4*)qsrc)[2 * u + 1];
      u32x4 o = {pack2(a[0], a[1]), pack2(a[2], a[3]),
                 pack2(b[0], b[1]), pack2(b[2], b[3])};
      ((u32x4*)qdst)[u] = o;
    }
  } else if (bx == 2048) {
    // compaction: cmp[0]=count; cmp[1..cnt]=ascending active slots;
    // cmp[1+cnt]=last active slot (pad for odd count).
    __shared__ int azs[32];
    if (tid < 32) {
      int z = 0;
#pragma unroll
      for (int r = 0; r < 20; ++r) z |= (mask[tid * 20 + r] == 0) ? 1 : 0;
      azs[tid] = z;
    }
    __syncthreads();
    if (tid < 64) {
      const int lane = tid;
      int base = 0;
      int lasts = 0;
      for (int it = 0; it < 10; ++it) {
        const int s = it * 64 + lane;
        const int bb = s / 20;
        const int actv = azs[bb] ? ((mask[s] == 0) ? 1 : 0) : 1;
        unsigned long long bal = __ballot(actv);
        const int off = (int)__popcll(bal & ((1ull << lane) - 1ull));
        if (actv) {
          cmp[1 + base + off] = s;
          lasts = s;
        }
        base += (int)__popcll(bal);
      }
#pragma unroll
      for (int d = 1; d < 64; d <<= 1) {
        int o = __shfl_xor(lasts, d);
        lasts = lasts > o ? lasts : o;
      }
      if (lane == 0) {
        cmp[0] = base;
        cmp[1 + base] = lasts;  // pad for odd count
      }
    }
  } else {
    // K sparse cvt (2048 blocks), self-computed active bitmap
    __shared__ unsigned char actb[640];
    __shared__ int azs[32];
    build_actb(mask, actb, azs, tid);
    cvt_sparse_body(ksrc, kdst, actb, (bx - 2049) * 256 + tid, 2048 * 256);
  }
}

// --------------- standalone sparse activation cvt (thin-ws V path) ---------
__global__ __launch_bounds__(256) void cvt_sp(const float* __restrict__ src,
                                              unsigned short* __restrict__ dst,
                                              const int* __restrict__ mask) {
  __shared__ unsigned char actb[640];
  __shared__ int azs[32];
  const int tid = (int)threadIdx.x;
  build_actb(mask, actb, azs, tid);
  cvt_sparse_body(src, dst, actb, (int)(blockIdx.x * 256) + tid,
                  (int)(gridDim.x * 256));
}

// ---------------- C[m,n] = sum_k A[m,k]*W[n,k] + bias[n] -------------------
// OUT_MODE: 0 = f32 row-major, 1 = bf16 row-major, 2 = bf16 per-head V^T.
// A is bf16, SPARSE/absolute slot layout; rows indirect via cs0/cs1 (for
// CMP=0, cs0/cs1 = 2mt/2mt+1 == dense).  Proven 0-conflict tiles,
// counted-vmcnt pipeline.  SC=1: epilogue x0.125.  CMP=1: chunked XCD
// swizzle + early exit on active count.
template <int OUT_MODE, int SC, int CMP>
DEVI void gemm_body(const void* __restrict__ Ain,
                    const unsigned short* __restrict__ W,
                    const float* __restrict__ bias, void* __restrict__ Cout,
                    int N, int K, int nnt, int nb, int bx,
                    const int* __restrict__ cmp, char* smem) {
  char* Asb = smem;
  char* Bsb = smem + 16384;
  const int tid = (int)threadIdx.x;
  const int lane = tid & 63, wave = tid >> 6;
  const int lm = lane & 15, l4 = lane >> 4;
  const int wr = wave >> 1, wc = wave & 1;

  // ---- tile mapping + slot mapping (64-row slots: cs0, cs1) ----
  int mt, nt, cs0, cs1;
  if (CMP) {
    const int cnt = cmp[0];
    const int tiles = (cnt + 1) >> 1;   // ceil(cnt/2)
    if (bx >= tiles * 8) return;        // uniform exit before any barrier
    const int lg = (bx & 7) * tiles + (bx >> 3);
    mt = lg / nnt;
    nt = lg % nnt;
    cs0 = cmp[1 + 2 * mt];
    cs1 = cmp[2 + 2 * mt];
  } else {
    const int lg = (bx & 7) * (nb >> 3) + (bx >> 3);
    mt = lg / nnt;
    nt = lg % nnt;
    cs0 = 2 * mt;
    cs1 = 2 * mt + 1;
  }

  f32x4 zero4 = {0.f, 0.f, 0.f, 0.f};
  f32x4 acc[4][4];
#pragma unroll
  for (int i = 0; i < 4; ++i)
#pragma unroll
    for (int j = 0; j < 4; ++j) acc[i][j] = zero4;

  // ---- staging mapping: row = tid>>2, 16B chunk = tid&3; T2 swizzle ----
  const int srow = tid >> 2, sblk = tid & 3;
  const int scb = sblk ^ ((srow >> 1) & 3);
  const unsigned short* wpg = W + (size_t)(nt * 128 + srow) * K + scb * 8;
  const int kx = (lm >> 1) & 3;

  // slot-indirect A bases (CMP=0: == dense mt*128 / mt*128+64 rows)
  const unsigned short* apg0 =
      (const unsigned short*)Ain + ((size_t)cs0 * 64 + srow) * K + scb * 8;
  const unsigned short* apg1 =
      (const unsigned short*)Ain + ((size_t)cs1 * 64 + srow) * K + scb * 8;
  const int NT = K >> 5;
#pragma unroll
  for (int t0 = 0; t0 < 2; ++t0) {
    const int kt = t0 * 32;
    gload_lds16(apg0 + kt, Asb + t0 * 8192 + tid * 16);
    gload_lds16(apg1 + kt, Asb + t0 * 8192 + 4096 + tid * 16);
    gload_lds16(wpg + kt, Bsb + t0 * 8192 + tid * 16);
    gload_lds16(wpg + (size_t)64 * K + kt, Bsb + t0 * 8192 + 4096 + tid * 16);
  }
  int cur = 0;
  for (int t = 0; t < NT; ++t) {
    if (t + 1 < NT)
      asm volatile("s_waitcnt vmcnt(4)" ::: "memory");
    else
      asm volatile("s_waitcnt vmcnt(0)" ::: "memory");
    asm volatile("s_barrier" ::: "memory");
    bf16x8 af[4], bfr[4];
#pragma unroll
    for (int i = 0; i < 4; ++i)
      af[i] = *(const bf16x8*)(Asb + cur * 8192 + (wr * 64 + i * 16 + lm) * 64 +
                               ((l4 ^ kx) * 16));
#pragma unroll
    for (int j = 0; j < 4; ++j)
      bfr[j] = *(const bf16x8*)(Bsb + cur * 8192 + (wc * 64 + j * 16 + lm) * 64 +
                                ((l4 ^ kx) * 16));
#pragma unroll
    for (int i = 0; i < 4; ++i)
#pragma unroll
      for (int j = 0; j < 4; ++j)
        acc[i][j] = __builtin_amdgcn_mfma_f32_16x16x32_bf16(af[i], bfr[j], acc[i][j], 0, 0, 0);
    asm volatile("s_barrier" ::: "memory");
    if (t + 2 < NT) {
      const int kt = (t + 2) * 32;
      gload_lds16(apg0 + kt, Asb + cur * 8192 + tid * 16);
      gload_lds16(apg1 + kt, Asb + cur * 8192 + 4096 + tid * 16);
      gload_lds16(wpg + kt, Bsb + cur * 8192 + tid * 16);
      gload_lds16(wpg + (size_t)64 * K + kt, Bsb + cur * 8192 + 4096 + tid * 16);
    }
    cur ^= 1;
  }

  const int c0o = nt * 128 + wc * 64 + lm;
  float bb[4];
#pragma unroll
  for (int j = 0; j < 4; ++j) bb[j] = bias[c0o + j * 16];
  const int mslot = wr ? cs1 : cs0;  // this wave's 64-row output slot

  if (OUT_MODE < 2) {
#pragma unroll
    for (int i = 0; i < 4; ++i)
#pragma unroll
      for (int j = 0; j < 4; ++j)
#pragma unroll
        for (int p = 0; p < 4; ++p) {
          size_t grow = (size_t)mslot * 64 + (l4 * 4 + i * 16 + p);
          size_t idx = grow * N + (size_t)(c0o + j * 16);
          float v = acc[i][j][p] + bb[j];
          if (SC) v *= 0.125f;  // exact exponent shift
          if (OUT_MODE == 1)
            ((unsigned short*)Cout)[idx] = f2bf(v);
          else
            ((float*)Cout)[idx] = v;
        }
  } else {
    // V^T per-head tiles: vt[(slot*16+h)*4096 + d*64 + t], t = i*16+l4*4+p
    const int hh = (nt * 128 + wc * 64) / 64;
    unsigned short* vt = (unsigned short*)Cout;
    const size_t base = ((size_t)mslot * 16 + hh) * 4096;
#pragma unroll
    for (int j = 0; j < 4; ++j) {
      const int d = lm + j * 16;
#pragma unroll
      for (int i = 0; i < 4; ++i) {
        uint2 wv;
        wv.x = pack2(acc[i][j][0] + bb[j], acc[i][j][1] + bb[j]);
        wv.y = pack2(acc[i][j][2] + bb[j], acc[i][j][3] + bb[j]);
        *(uint2*)(vt + base + (size_t)d * 64 + i * 16 + l4 * 4) = wv;
      }
    }
  }
}

// ---- merged Q+K projection (thin-ws path) ----
__global__ __launch_bounds__(256, 4) void gemm_qk(
    const unsigned short* __restrict__ aq, const unsigned short* __restrict__ wq,
    const float* __restrict__ bq, unsigned short* __restrict__ qout,
    const unsigned short* __restrict__ ak, const unsigned short* __restrict__ wk,
    const float* __restrict__ bk, unsigned short* __restrict__ kout,
    const int* __restrict__ cmp) {
  __shared__ __align__(16) char smem[32768];
  const int bx = (int)blockIdx.x;
  if (bx < 256)
    gemm_body<1, 1, 0>(aq, wq, bq, qout, 1024, 1024, 8, 256, bx, cmp, smem);
  else
    gemm_body<1, 0, 1>(ak, wk, bk, kout, 1024, 1024, 8, 2560, bx - 256, cmp, smem);
}

// ---- merged Q+K projection + V sparse-cvt (fat-ws path) ----
// bx<256: Q; bx<2816: K; else (2048 blocks): V sparse cvt -> act_v.
__global__ __launch_bounds__(256, 4) void gemm_qkv(
    const unsigned short* __restrict__ aq, const unsigned short* __restrict__ wq,
    const float* __restrict__ bq, unsigned short* __restrict__ qout,
    const unsigned short* __restrict__ ak, const unsigned short* __restrict__ wk,
    const float* __restrict__ bk, unsigned short* __restrict__ kout,
    const float* __restrict__ vsrc, unsigned short* __restrict__ vdst,
    const int* __restrict__ mask, const int* __restrict__ cmp) {
  __shared__ __align__(16) char smem[32768];
  const int bx = (int)blockIdx.x;
  const int tid = (int)threadIdx.x;
  if (bx < 256) {
    gemm_body<1, 1, 0>(aq, wq, bq, qout, 1024, 1024, 8, 256, bx, cmp, smem);
  } else if (bx < 256 + 2560) {
    gemm_body<1, 0, 1>(ak, wk, bk, kout, 1024, 1024, 8, 2560, bx - 256, cmp, smem);
  } else {
    unsigned char* actb = (unsigned char*)smem;       // 640 B
    int* azs = (int*)(smem + 640);                    // 128 B (4-aligned)
    build_actb(mask, actb, azs, tid);
    cvt_sparse_body(vsrc, vdst, actb, (bx - 2816) * 256 + tid, 2048 * 256);
  }
}

// ---- V projection (CMP=1, V^T output) ----
__global__ __launch_bounds__(256, 4) void gemm_v(
    const unsigned short* __restrict__ av, const unsigned short* __restrict__ wv,
    const float* __restrict__ bv, unsigned short* __restrict__ vout,
    const int* __restrict__ cmp) {
  __shared__ __align__(16) char smem[32768];
  gemm_body<2, 0, 1>(av, wv, bv, vout, 1024, 1024, 8, 2560, (int)blockIdx.x, cmp, smem);
}

// ---- out projection (CMP=0, f32 output) ----
__global__ __launch_bounds__(256, 4) void gemm_out(
    const unsigned short* __restrict__ am, const unsigned short* __restrict__ wo,
    const float* __restrict__ bo, float* __restrict__ oout,
    const int* __restrict__ cmp) {
  __shared__ __align__(16) char smem[32768];
  gemm_body<0, 0, 0>(am, wo, bo, oout, 1024, 1024, 8, 256, (int)blockIdx.x, cmp, smem);
}

// ----------------------------- fused attention -----------------------------
// One block per (h, b); 8 waves, wave w owns q rows [16w,16w+16).
// Swapped-operand MFMAs so q = lane&15 everywhere; online softmax over r.
// LDS (48KB): kv_s[2][K,V] 32KB; pa_s 16KB; q/sa^T staging overlays.
// launch_bounds (512,4): PROVEN config (do not raise min-waves: round-23's
// (512,6) squeezed VGPR 64->40 and spilled).
// Active-review compaction: reviews with mask==1 (when any mask==0 exists in
// row b) have pooled weight exactly 0.0f (expf(-1e30 - max) underflows) ->
// skipped entirely.  Bitmask is uniform per block (depends only on b).
__global__ __launch_bounds__(512, 4) void attn2(
    const unsigned short* __restrict__ qb, const unsigned short* __restrict__ kb,
    const unsigned short* __restrict__ vtg, const int* __restrict__ mask,
    const int* __restrict__ mask2, const float* __restrict__ sa_a,
    const float* __restrict__ sa_b, unsigned short* __restrict__ merged) {
  const int h = (int)blockIdx.x;
  const int b = (int)blockIdx.y;
  const int tid = (int)threadIdx.x;
  const int lane = tid & 63, wave = tid >> 6;
  const int lm = lane & 15, l4 = lane >> 4;
  const int sw = (lm & 7) << 4;

  __shared__ unsigned short kv_s[2][2][64 * 64];  // [buf][0=K [t][d], 1=V^T [d][t]]
  __shared__ unsigned short pa_s[8 * 16 * 64];    // wave-private P/att rows

  char* kvb0 = (char*)kv_s;          // buf stride 16384; V^T at +8192
  char* qreg = (char*)kv_s + 16384;  // q staging region = buf1 (dead after hoist)
  char* satb = (char*)pa_s;          // sa^T staging (dead after hoist)

  // ---- active-review bitmask (uniform across the block) ----
  unsigned am = 0u;
#pragma unroll
  for (int rr = 0; rr < 20; ++rr)
    am |= (mask[b * 20 + rr] == 0) ? (1u << rr) : 0u;
  const unsigned act = am ? am : 0xFFFFFu;

  // ---- stage Q into qreg (pre-swizzled source columns) ----
#pragma unroll
  for (int s = 0; s < 2; ++s) {
    int idx = s * 512 + tid, row = idx >> 3, blk = idx & 7;
    int cb = blk ^ (row & 7);
    gload_lds16(qb + (size_t)(b * 128 + row) * 1024 + h * 64 + cb * 8, qreg + idx * 16);
  }
  // ---- stage sa^T into satb: sat[jj][d] = sa_a[d][jj], swizzled ----
#pragma unroll
  for (int s = 0; s < 8; ++s) {
    int idx = s * 512 + tid, jj = idx & 63, d = idx >> 6;
    *(unsigned short*)(satb + jj * 128 + ((d * 2) ^ ((jj & 7) << 4))) =
        f2bf(sa_a[d * 64 + jj]);
  }
  // ---- stage first ACTIVE review K/V into buf0 ----
  const int srow = tid >> 3, sblk = tid & 7;
  const int scb = sblk ^ (srow & 7);
  int r = (int)__builtin_ctz(act);
  unsigned rem = act & (act - 1u);
  gload_lds16(kb + ((size_t)(b * 20 + r) * 64 + srow) * 1024 + h * 64 + scb * 8,
              kvb0 + tid * 16);
  gload_lds16(vtg + ((size_t)(b * 20 + r) * 16 + h) * 4096 + srow * 64 + scb * 8,
              kvb0 + 8192 + tid * 16);

  f32x4 sbv[4];
#pragma unroll
  for (int i = 0; i < 4; ++i) sbv[i] = *(const f32x4*)(sa_b + i * 16 + l4 * 4);

  __syncthreads();  // qreg, satb, buf0 all visible

  // ---- hoist Q B-fragments and sa^T A-fragments to registers ----
  const char* qrp = qreg + (wave * 16 + lm) * 128;
  bf16x8 qf[2];
  qf[0] = *(const bf16x8*)(qrp + ((l4 * 16) ^ sw));
  qf[1] = *(const bf16x8*)(qrp + ((64 + l4 * 16) ^ sw));
  bf16x8 sfr[2][4];
#pragma unroll
  for (int kk = 0; kk < 2; ++kk)
#pragma unroll
    for (int i = 0; i < 4; ++i)
      sfr[kk][i] = *(const bf16x8*)(satb + (i * 16 + lm) * 128 +
                                    ((kk * 64 + l4 * 16) ^ sw));
  asm volatile("s_waitcnt lgkmcnt(0)" ::: "memory");  // hoist reads retired
  __syncthreads();  // all waves done -> qreg/satb reusable as buf1 / P-rows

  char* pw = (char*)pa_s + wave * 2048 + lm * 128;  // wave-private row q=lm

  f32x4 zero4 = {0.f, 0.f, 0.f, 0.f};
  f32x4 Pacc[4];
#pragma unroll
  for (int i = 0; i < 4; ++i) Pacc[i] = zero4;
  float m_run = -3.0e38f, s_run = 0.0f;

  int it = 0;
  for (;;) {
    const int pb = it & 1;
    if (it) __syncthreads();  // buf[pb] staged; all waves done with buf[1-pb]
    const int nr = rem ? (int)__builtin_ctz(rem) : -1;
    if (nr >= 0) {  // stage next active review (flies under this one's compute)
      const int nbuf = pb ^ 1;
      gload_lds16(kb + ((size_t)(b * 20 + nr) * 64 + srow) * 1024 + h * 64 + scb * 8,
                  kvb0 + nbuf * 16384 + tid * 16);
      gload_lds16(vtg + ((size_t)(b * 20 + nr) * 16 + h) * 4096 + srow * 64 + scb * 8,
                  kvb0 + nbuf * 16384 + 8192 + tid * 16);
    }
    const char* kbse = kvb0 + pb * 16384;
    const char* vbse = kvb0 + pb * 16384 + 8192;

    // ---- mask2 loads issued BEFORE the MFMA cluster (latency hides) ----
    const int mbase = (b * 20 + r) * 64;
    int4 m2v[4];
#pragma unroll
    for (int i = 0; i < 4; ++i)
      m2v[i] = *(const int4*)(mask2 + mbase + i * 16 + l4 * 4);

    // ---- S^T = mfma(K, Q): rows t, col q (q pre-scaled by 1/8) ----
    f32x4 sc[4];
#pragma unroll
    for (int i = 0; i < 4; ++i) sc[i] = zero4;
    __builtin_amdgcn_s_setprio(1);
#pragma unroll
    for (int kk = 0; kk < 2; ++kk) {
      bf16x8 kf[4];
#pragma unroll
      for (int i = 0; i < 4; ++i)
        kf[i] = *(const bf16x8*)(kbse + (i * 16 + lm) * 128 + ((kk * 64 + l4 * 16) ^ sw));
#pragma unroll
      for (int i = 0; i < 4; ++i)
        sc[i] = __builtin_amdgcn_mfma_f32_16x16x32_bf16(kf[i], qf[kk], sc[i], 0, 0, 0);
    }
    __builtin_amdgcn_s_setprio(0);

    // ---- token mask (scores already scaled) + softmax over t ----
#pragma unroll
    for (int i = 0; i < 4; ++i) {
      sc[i][0] = (m2v[i].x == 0) ? -1e20f : sc[i][0];
      sc[i][1] = (m2v[i].y == 0) ? -1e20f : sc[i][1];
      sc[i][2] = (m2v[i].z == 0) ? -1e20f : sc[i][2];
      sc[i][3] = (m2v[i].w == 0) ? -1e20f : sc[i][3];
    }
    float mx = sc[0][0];
#pragma unroll
    for (int i = 0; i < 4; ++i)
#pragma unroll
      for (int p = 0; p < 4; ++p) mx = fmaxf(mx, sc[i][p]);
    mx = fmaxf(mx, __shfl_xor(mx, 16));
    mx = fmaxf(mx, __shfl_xor(mx, 32));
    float sum = 0.f;
#pragma unroll
    for (int i = 0; i < 4; ++i)
#pragma unroll
      for (int p = 0; p < 4; ++p) {
        float e = __expf(sc[i][p] - mx);
        sc[i][p] = e;
        sum += e;
      }
    sum += __shfl_xor(sum, 16);
    sum += __shfl_xor(sum, 32);
    const float pinv = __builtin_amdgcn_rcpf(sum);

    // ---- P -> wave-private LDS [q][t], packed 8B swizzled writes ----
#pragma unroll
    for (int i = 0; i < 4; ++i) {
      uint2 wv;
      wv.x = cvtpk(sc[i][0] * pinv, sc[i][1] * pinv);
      wv.y = cvtpk(sc[i][2] * pinv, sc[i][3] * pinv);
      *(uint2*)(pw + ((i * 32 + l4 * 8) ^ sw)) = wv;
    }

    // ---- att^T = mfma(V^T, P): rows d, col q ----
    f32x4 av[4];
#pragma unroll
    for (int i = 0; i < 4; ++i) av[i] = zero4;
    __builtin_amdgcn_s_setprio(1);
#pragma unroll
    for (int kk = 0; kk < 2; ++kk) {
      bf16x8 pf = *(const bf16x8*)(pw + ((kk * 64 + l4 * 16) ^ sw));
      bf16x8 vf[4];
#pragma unroll
      for (int i = 0; i < 4; ++i)
        vf[i] = *(const bf16x8*)(vbse + (i * 16 + lm) * 128 + ((kk * 64 + l4 * 16) ^ sw));
#pragma unroll
      for (int i = 0; i < 4; ++i)
        av[i] = __builtin_amdgcn_mfma_f32_16x16x32_bf16(vf[i], pf, av[i], 0, 0, 0);
    }
    __builtin_amdgcn_s_setprio(0);

    // ---- att -> same wave-private LDS [q][d] (P already consumed) ----
#pragma unroll
    for (int i = 0; i < 4; ++i) {
      uint2 wv;
      wv.x = cvtpk(av[i][0], av[i][1]);
      wv.y = cvtpk(av[i][2], av[i][3]);
      *(uint2*)(pw + ((i * 32 + l4 * 8) ^ sw)) = wv;
    }

    // ---- e^T = mfma(sa^T, att): rows jj, col q ----
    f32x4 ep[4];
#pragma unroll
    for (int i = 0; i < 4; ++i) ep[i] = zero4;
    __builtin_amdgcn_s_setprio(1);
#pragma unroll
    for (int kk = 0; kk < 2; ++kk) {
      bf16x8 afr = *(const bf16x8*)(pw + ((kk * 64 + l4 * 16) ^ sw));
#pragma unroll
      for (int i = 0; i < 4; ++i)
        ep[i] = __builtin_amdgcn_mfma_f32_16x16x32_bf16(sfr[kk][i], afr, ep[i], 0, 0, 0);
    }
    __builtin_amdgcn_s_setprio(0);
    float a = 0.f;
#pragma unroll
    for (int i = 0; i < 4; ++i)
#pragma unroll
      for (int p = 0; p < 4; ++p) a += fast_tanh(ep[i][p]) * sbv[i][p];
    a += __shfl_xor(a, 16);
    a += __shfl_xor(a, 32);

    // ---- exact online softmax update over active reviews ----
    const float e_r = a;
    const float mnew = fmaxf(m_run, e_r);
    const float scl = __expf(m_run - mnew);
    const float w = __expf(e_r - mnew);
    s_run = s_run * scl + w;
#pragma unroll
    for (int i = 0; i < 4; ++i)
#pragma unroll
      for (int p = 0; p < 4; ++p) Pacc[i][p] = Pacc[i][p] * scl + w * av[i][p];
    m_run = mnew;

    if (nr < 0) break;
    r = nr;
    rem &= rem - 1u;
    ++it;
  }

  // ---- merged[b*128+q][h*64+d] = bf16(Pacc / s) ----
  const float inv_s = __builtin_amdgcn_rcpf(s_run);
  unsigned short* mrow = merged + (size_t)(b * 128 + wave * 16 + lm) * 1024 + h * 64;
#pragma unroll
  for (int i = 0; i < 4; ++i) {
    uint2 o;
    o.x = cvtpk(Pacc[i][0] * inv_s, Pacc[i][1] * inv_s);
    o.y = cvtpk(Pacc[i][2] * inv_s, Pacc[i][3] * inv_s);
    *(uint2*)(mrow + i * 16 + l4 * 4) = o;
  }
}

// ---------------------------------------------------------------------------
extern "C" void kernel_launch(void* const* d_in, const int* in_sizes, int n_in,
                              void* d_out, int out_size, void* d_ws, size_t ws_size,
                              hipStream_t stream) {
  (void)in_sizes; (void)n_in; (void)out_size;
  const float* query = (const float*)d_in[0];
  const float* key   = (const float*)d_in[1];
  const float* value = (const float*)d_in[2];
  const int*   mask  = (const int*)d_in[3];
  const int*   mask2 = (const int*)d_in[4];
  const float* Wq = (const float*)d_in[5];
  const float* bq = (const float*)d_in[6];
  const float* Wk = (const float*)d_in[7];
  const float* bk = (const float*)d_in[8];
  const float* Wv = (const float*)d_in[9];
  const float* bv = (const float*)d_in[10];
  const float* Wo = (const float*)d_in[11];
  const float* bo = (const float*)d_in[12];
  const float* sa_a = (const float*)d_in[13];
  const float* sa_b = (const float*)d_in[14];

  char* ws = (char*)d_ws;
  size_t off = 0;
  auto carve = [&](size_t bytes) -> char* {
    char* p = ws + off;
    off += (bytes + 255) & ~(size_t)255;
    return p;
  };
  unsigned short* wq_b = (unsigned short*)carve((size_t)1024 * 1024 * 2);
  unsigned short* wk_b = (unsigned short*)carve((size_t)1024 * 1024 * 2);
  unsigned short* wv_b = (unsigned short*)carve((size_t)1024 * 1024 * 2);
  unsigned short* wo_b = (unsigned short*)carve((size_t)1024 * 1024 * 2);
  unsigned short* q_b  = (unsigned short*)carve((size_t)4096 * 1024 * 2);
  unsigned short* k_b  = (unsigned short*)carve((size_t)40960 * 1024 * 2);
  unsigned short* vt_g = (unsigned short*)carve((size_t)40960 * 1024 * 2);
  unsigned short* mrg  = (unsigned short*)carve((size_t)4096 * 1024 * 2);
  int* cmp = (int*)carve(4096);
  unsigned short* act = (unsigned short*)carve((size_t)40960 * 1024 * 2);
  unsigned short* act_q = (unsigned short*)carve((size_t)4096 * 1024 * 2);

  const size_t actv_bytes = (size_t)40960 * 1024 * 2;
  const bool fat = ws_size >= off + actv_bytes + (1 << 20);

  // prep: weights cvt + Q cvt + compaction + K sparse-cvt, one dispatch
  prep<<<4097, 256, 0, stream>>>(Wq, Wk, Wv, Wo, wq_b, wk_b, wv_b, wo_b,
                                 query, act_q, key, act, mask, cmp);

  if (fat) {
    // Q + K projections + V sparse-cvt in one dispatch (cvt rides the tail)
    unsigned short* act_v = (unsigned short*)carve(actv_bytes);
    gemm_qkv<<<256 + 2560 + 2048, 256, 0, stream>>>(
        act_q, wq_b, bq, q_b, act, wk_b, bk, k_b, value, act_v, mask, cmp);
    gemm_v<<<2560, 256, 0, stream>>>(act_v, wv_b, bv, vt_g, cmp);
  } else {
    gemm_qk<<<256 + 2560, 256, 0, stream>>>(act_q, wq_b, bq, q_b,
                                            act, wk_b, bk, k_b, cmp);
    cvt_sp<<<2048, 256, 0, stream>>>(value, act, mask);
    gemm_v<<<2560, 256, 0, stream>>>(act, wv_b, bv, vt_g, cmp);
  }

  attn2<<<dim3(16, 32), 512, 0, stream>>>(q_b, k_b, vt_g, mask, mask2, sa_a, sa_b, mrg);

  gemm_out<<<256, 256, 0, stream>>>(mrg, wo_b, bo, (float*)d_out, cmp);
}

// Round 15
// 253.381 us; speedup vs baseline: 1.4345x; 1.0007x over previous
//
#include <hip/hip_runtime.h>
#include <stdint.h>

// ---------------------------------------------------------------------------
// FineReviewDecoderAttention: prep (weights cvt + Q cvt + compaction + K
// sparse-cvt) -> gemm_qkv (Q-proj + K-proj + V sparse-cvt, ONE dispatch,
// ws-guarded) -> V-proj -> fused attention -> out proj.
// B=32 Q=128 D=1024 H=16 d=64 R=20.
// Delta vs round 26 (passed, 255.0us = best): V sparse-cvt (~20us, fully
// serial between gemm_qk and gemm_v, independent of both) folded into the
// Q+K GEMM dispatch as a third block range (gemm blocks FIRST so K-gemm's
// critical path is not delayed; cvt blocks fill the retirement tail).  The
// GEMM dispatch is compute/latency-bound (HBM ~13%) so the streaming cvt
// rides along nearly free.  Needs act(K) + act_v(V) live simultaneously
// (+80MB ws) -> GUARDED: if ws_size is insufficient, exact round-26 serial
// path (gemm_qk + cvt_sp) runs instead.  All GEMM bodies / prep / attn2 /
// out-proj byte-identical to round 26.
// ---------------------------------------------------------------------------

typedef __attribute__((ext_vector_type(8))) short bf16x8;
typedef __attribute__((ext_vector_type(4))) float f32x4;
typedef __attribute__((ext_vector_type(4))) unsigned int u32x4;
typedef __attribute__((address_space(1))) const unsigned int as1_t;
typedef __attribute__((address_space(3))) unsigned int as3_t;

#define DEVI static __device__ __forceinline__

DEVI unsigned short f2bf(float f) {  // RNE f32->bf16 (finite inputs)
  unsigned int u = __float_as_uint(f);
  u += 0x7fffu + ((u >> 16) & 1u);
  return (unsigned short)(u >> 16);
}
DEVI unsigned int pack2(float a, float b) {
  return (unsigned int)f2bf(a) | ((unsigned int)f2bf(b) << 16);
}
// HW packed f32->bf16 (RNE): a -> lo16, b -> hi16.  (round-16-proven)
DEVI unsigned int cvtpk(float a, float b) {
  unsigned int r;
  asm("v_cvt_pk_bf16_f32 %0, %1, %2" : "=v"(r) : "v"(a), "v"(b));
  return r;
}

DEVI void gload_lds16(const void* g, void* l) {
  __builtin_amdgcn_global_load_lds((as1_t*)g, (as3_t*)l, 16, 0, 0);
}

DEVI float fast_tanh(float x) {  // round-5-proven form
  float ax = fabsf(x);
  float e = __expf(2.0f * ax);
  float r = __builtin_fmaf(-2.0f, __builtin_amdgcn_rcpf(e + 1.0f), 1.0f);
  return copysignf(r, x);
}

// ---- sparse activation cvt helper: convert active slots, absolute layout.
// actb: 640-entry active bitmap (LDS).  Unit = 8 elements; dst idx = src idx.
DEVI void cvt_sparse_body(const float* __restrict__ src,
                          unsigned short* __restrict__ dst,
                          const unsigned char* actb, int gid, int stride) {
  for (int u = gid; u < 640 * 8192; u += stride) {
    const int s = u >> 13;
    if (!actb[s]) continue;
    f32x4 a = *(const f32x4*)(src + (size_t)u * 8);
    f32x4 b = *(const f32x4*)(src + (size_t)u * 8 + 4);
    u32x4 o = {pack2(a[0], a[1]), pack2(a[2], a[3]),
               pack2(b[0], b[1]), pack2(b[2], b[3])};
    *(u32x4*)(dst + (size_t)u * 8) = o;
  }
}

// build the 640-entry active bitmap in LDS (azs: per-batch any-zero)
DEVI void build_actb(const int* __restrict__ mask, unsigned char* actb,
                     int* azs, int tid) {
  if (tid < 32) {
    int z = 0;
#pragma unroll
    for (int r = 0; r < 20; ++r) z |= (mask[tid * 20 + r] == 0) ? 1 : 0;
    azs[tid] = z;
  }
  __syncthreads();
  for (int s = tid; s < 640; s += 256)
    actb[s] = azs[s / 20] ? ((mask[s] == 0) ? 1 : 0) : 1;
  __syncthreads();
}

// ------- prep: weights f32->bf16, Q f32->bf16, compaction, K sparse-cvt ----
// blocks 0..1023: weight cvt; 1024..2047: Q cvt; 2048: compaction;
// 2049..4096: K sparse cvt (self-computed active bitmap, no cmp dep).
__global__ __launch_bounds__(256) void prep(
    const float* __restrict__ w0, const float* __restrict__ w1,
    const float* __restrict__ w2, const float* __restrict__ w3,
    unsigned short* __restrict__ o0, unsigned short* __restrict__ o1,
    unsigned short* __restrict__ o2, unsigned short* __restrict__ o3,
    const float* __restrict__ qsrc, unsigned short* __restrict__ qdst,
    const float* __restrict__ ksrc, unsigned short* __restrict__ kdst,
    const int* __restrict__ mask, int* __restrict__ cmp) {
  const int bx = (int)blockIdx.x;
  const int tid = (int)threadIdx.x;
  if (bx < 1024) {
    const int i = bx * 256 + tid;  // < 262144 by construction
    f32x4 v;
    uint2 a;
    v = ((const f32x4*)w0)[i]; a.x = pack2(v[0], v[1]); a.y = pack2(v[2], v[3]);
    *(uint2*)(o0 + 4 * (size_t)i) = a;
    v = ((const f32x4*)w1)[i]; a.x = pack2(v[0], v[1]); a.y = pack2(v[2], v[3]);
    *(uint2*)(o1 + 4 * (size_t)i) = a;
    v = ((const f32x4*)w2)[i]; a.x = pack2(v[0], v[1]); a.y = pack2(v[2], v[3]);
    *(uint2*)(o2 + 4 * (size_t)i) = a;
    v = ((const f32x4*)w3)[i]; a.x = pack2(v[0], v[1]); a.y = pack2(v[2], v[3]);
    *(uint2*)(o3 + 4 * (size_t)i) = a;
  } else if (bx < 2048) {
    // Q: 524288 units of 8 f32; thread handles units i and i+262144.
    const int i = (bx - 1024) * 256 + tid;
#pragma unroll
    for (int h = 0; h < 2; ++h) {
      const int u = i + h * 262144;
      f32x4 a = ((const f32x4*)qsrc)[2 * u];
      f32x4 b = ((const f32x4*)qsrc)[2 * u + 1];
      u32x4 o = {pack2(a[0], a[1]), pack2(a[2], a[3]),
                 pack2(b[0], b[1]), pack2(b[2], b[3])};
      ((u32x4*)qdst)[u] = o;
    }
  } else if (bx == 2048) {
    // compaction: cmp[0]=count; cmp[1..cnt]=ascending active slots;
    // cmp[1+cnt]=last active slot (pad for odd count).
    __shared__ int azs[32];
    if (tid < 32) {
      int z = 0;
#pragma unroll
      for (int r = 0; r < 20; ++r) z |= (mask[tid * 20 + r] == 0) ? 1 : 0;
      azs[tid] = z;
    }
    __syncthreads();
    if (tid < 64) {
      const int lane = tid;
      int base = 0;
      int lasts = 0;
      for (int it = 0; it < 10; ++it) {
        const int s = it * 64 + lane;
        const int bb = s / 20;
        const int actv = azs[bb] ? ((mask[s] == 0) ? 1 : 0) : 1;
        unsigned long long bal = __ballot(actv);
        const int off = (int)__popcll(bal & ((1ull << lane) - 1ull));
        if (actv) {
          cmp[1 + base + off] = s;
          lasts = s;
        }
        base += (int)__popcll(bal);
      }
#pragma unroll
      for (int d = 1; d < 64; d <<= 1) {
        int o = __shfl_xor(lasts, d);
        lasts = lasts > o ? lasts : o;
      }
      if (lane == 0) {
        cmp[0] = base;
        cmp[1 + base] = lasts;  // pad for odd count
      }
    }
  } else {
    // K sparse cvt (2048 blocks), self-computed active bitmap
    __shared__ unsigned char actb[640];
    __shared__ int azs[32];
    build_actb(mask, actb, azs, tid);
    cvt_sparse_body(ksrc, kdst, actb, (bx - 2049) * 256 + tid, 2048 * 256);
  }
}

// --------------- standalone sparse activation cvt (thin-ws V path) ---------
__global__ __launch_bounds__(256) void cvt_sp(const float* __restrict__ src,
                                              unsigned short* __restrict__ dst,
                                              const int* __restrict__ mask) {
  __shared__ unsigned char actb[640];
  __shared__ int azs[32];
  const int tid = (int)threadIdx.x;
  build_actb(mask, actb, azs, tid);
  cvt_sparse_body(src, dst, actb, (int)(blockIdx.x * 256) + tid,
                  (int)(gridDim.x * 256));
}

// ---------------- C[m,n] = sum_k A[m,k]*W[n,k] + bias[n] -------------------
// OUT_MODE: 0 = f32 row-major, 1 = bf16 row-major, 2 = bf16 per-head V^T.
// A is bf16, SPARSE/absolute slot layout; rows indirect via cs0/cs1 (for
// CMP=0, cs0/cs1 = 2mt/2mt+1 == dense).  Proven 0-conflict tiles,
// counted-vmcnt pipeline.  SC=1: epilogue x0.125.  CMP=1: chunked XCD
// swizzle + early exit on active count.
template <int OUT_MODE, int SC, int CMP>
DEVI void gemm_body(const void* __restrict__ Ain,
                    const unsigned short* __restrict__ W,
                    const float* __restrict__ bias, void* __restrict__ Cout,
                    int N, int K, int nnt, int nb, int bx,
                    const int* __restrict__ cmp, char* smem) {
  char* Asb = smem;
  char* Bsb = smem + 16384;
  const int tid = (int)threadIdx.x;
  const int lane = tid & 63, wave = tid >> 6;
  const int lm = lane & 15, l4 = lane >> 4;
  const int wr = wave >> 1, wc = wave & 1;

  // ---- tile mapping + slot mapping (64-row slots: cs0, cs1) ----
  int mt, nt, cs0, cs1;
  if (CMP) {
    const int cnt = cmp[0];
    const int tiles = (cnt + 1) >> 1;   // ceil(cnt/2)
    if (bx >= tiles * 8) return;        // uniform exit before any barrier
    const int lg = (bx & 7) * tiles + (bx >> 3);
    mt = lg / nnt;
    nt = lg % nnt;
    cs0 = cmp[1 + 2 * mt];
    cs1 = cmp[2 + 2 * mt];
  } else {
    const int lg = (bx & 7) * (nb >> 3) + (bx >> 3);
    mt = lg / nnt;
    nt = lg % nnt;
    cs0 = 2 * mt;
    cs1 = 2 * mt + 1;
  }

  f32x4 zero4 = {0.f, 0.f, 0.f, 0.f};
  f32x4 acc[4][4];
#pragma unroll
  for (int i = 0; i < 4; ++i)
#pragma unroll
    for (int j = 0; j < 4; ++j) acc[i][j] = zero4;

  // ---- staging mapping: row = tid>>2, 16B chunk = tid&3; T2 swizzle ----
  const int srow = tid >> 2, sblk = tid & 3;
  const int scb = sblk ^ ((srow >> 1) & 3);
  const unsigned short* wpg = W + (size_t)(nt * 128 + srow) * K + scb * 8;
  const int kx = (lm >> 1) & 3;

  // slot-indirect A bases (CMP=0: == dense mt*128 / mt*128+64 rows)
  const unsigned short* apg0 =
      (const unsigned short*)Ain + ((size_t)cs0 * 64 + srow) * K + scb * 8;
  const unsigned short* apg1 =
      (const unsigned short*)Ain + ((size_t)cs1 * 64 + srow) * K + scb * 8;
  const int NT = K >> 5;
#pragma unroll
  for (int t0 = 0; t0 < 2; ++t0) {
    const int kt = t0 * 32;
    gload_lds16(apg0 + kt, Asb + t0 * 8192 + tid * 16);
    gload_lds16(apg1 + kt, Asb + t0 * 8192 + 4096 + tid * 16);
    gload_lds16(wpg + kt, Bsb + t0 * 8192 + tid * 16);
    gload_lds16(wpg + (size_t)64 * K + kt, Bsb + t0 * 8192 + 4096 + tid * 16);
  }
  int cur = 0;
  for (int t = 0; t < NT; ++t) {
    if (t + 1 < NT)
      asm volatile("s_waitcnt vmcnt(4)" ::: "memory");
    else
      asm volatile("s_waitcnt vmcnt(0)" ::: "memory");
    asm volatile("s_barrier" ::: "memory");
    bf16x8 af[4], bfr[4];
#pragma unroll
    for (int i = 0; i < 4; ++i)
      af[i] = *(const bf16x8*)(Asb + cur * 8192 + (wr * 64 + i * 16 + lm) * 64 +
                               ((l4 ^ kx) * 16));
#pragma unroll
    for (int j = 0; j < 4; ++j)
      bfr[j] = *(const bf16x8*)(Bsb + cur * 8192 + (wc * 64 + j * 16 + lm) * 64 +
                                ((l4 ^ kx) * 16));
#pragma unroll
    for (int i = 0; i < 4; ++i)
#pragma unroll
      for (int j = 0; j < 4; ++j)
        acc[i][j] = __builtin_amdgcn_mfma_f32_16x16x32_bf16(af[i], bfr[j], acc[i][j], 0, 0, 0);
    asm volatile("s_barrier" ::: "memory");
    if (t + 2 < NT) {
      const int kt = (t + 2) * 32;
      gload_lds16(apg0 + kt, Asb + cur * 8192 + tid * 16);
      gload_lds16(apg1 + kt, Asb + cur * 8192 + 4096 + tid * 16);
      gload_lds16(wpg + kt, Bsb + cur * 8192 + tid * 16);
      gload_lds16(wpg + (size_t)64 * K + kt, Bsb + cur * 8192 + 4096 + tid * 16);
    }
    cur ^= 1;
  }

  const int c0o = nt * 128 + wc * 64 + lm;
  float bb[4];
#pragma unroll
  for (int j = 0; j < 4; ++j) bb[j] = bias[c0o + j * 16];
  const int mslot = wr ? cs1 : cs0;  // this wave's 64-row output slot

  if (OUT_MODE < 2) {
#pragma unroll
    for (int i = 0; i < 4; ++i)
#pragma unroll
      for (int j = 0; j < 4; ++j)
#pragma unroll
        for (int p = 0; p < 4; ++p) {
          size_t grow = (size_t)mslot * 64 + (l4 * 4 + i * 16 + p);
          size_t idx = grow * N + (size_t)(c0o + j * 16);
          float v = acc[i][j][p] + bb[j];
          if (SC) v *= 0.125f;  // exact exponent shift
          if (OUT_MODE == 1)
            ((unsigned short*)Cout)[idx] = f2bf(v);
          else
            ((float*)Cout)[idx] = v;
        }
  } else {
    // V^T per-head tiles: vt[(slot*16+h)*4096 + d*64 + t], t = i*16+l4*4+p
    const int hh = (nt * 128 + wc * 64) / 64;
    unsigned short* vt = (unsigned short*)Cout;
    const size_t base = ((size_t)mslot * 16 + hh) * 4096;
#pragma unroll
    for (int j = 0; j < 4; ++j) {
      const int d = lm + j * 16;
#pragma unroll
      for (int i = 0; i < 4; ++i) {
        uint2 wv;
        wv.x = pack2(acc[i][j][0] + bb[j], acc[i][j][1] + bb[j]);
        wv.y = pack2(acc[i][j][2] + bb[j], acc[i][j][3] + bb[j]);
        *(uint2*)(vt + base + (size_t)d * 64 + i * 16 + l4 * 4) = wv;
      }
    }
  }
}

// ---- merged Q+K projection (thin-ws path) ----
__global__ __launch_bounds__(256, 4) void gemm_qk(
    const unsigned short* __restrict__ aq, const unsigned short* __restrict__ wq,
    const float* __restrict__ bq, unsigned short* __restrict__ qout,
    const unsigned short* __restrict__ ak, const unsigned short* __restrict__ wk,
    const float* __restrict__ bk, unsigned short* __restrict__ kout,
    const int* __restrict__ cmp) {
  __shared__ __align__(16) char smem[32768];
  const int bx = (int)blockIdx.x;
  if (bx < 256)
    gemm_body<1, 1, 0>(aq, wq, bq, qout, 1024, 1024, 8, 256, bx, cmp, smem);
  else
    gemm_body<1, 0, 1>(ak, wk, bk, kout, 1024, 1024, 8, 2560, bx - 256, cmp, smem);
}

// ---- merged Q+K projection + V sparse-cvt (fat-ws path) ----
// bx<256: Q; bx<2816: K; else (2048 blocks): V sparse cvt -> act_v.
__global__ __launch_bounds__(256, 4) void gemm_qkv(
    const unsigned short* __restrict__ aq, const unsigned short* __restrict__ wq,
    const float* __restrict__ bq, unsigned short* __restrict__ qout,
    const unsigned short* __restrict__ ak, const unsigned short* __restrict__ wk,
    const float* __restrict__ bk, unsigned short* __restrict__ kout,
    const float* __restrict__ vsrc, unsigned short* __restrict__ vdst,
    const int* __restrict__ mask, const int* __restrict__ cmp) {
  __shared__ __align__(16) char smem[32768];
  const int bx = (int)blockIdx.x;
  const int tid = (int)threadIdx.x;
  if (bx < 256) {
    gemm_body<1, 1, 0>(aq, wq, bq, qout, 1024, 1024, 8, 256, bx, cmp, smem);
  } else if (bx < 256 + 2560) {
    gemm_body<1, 0, 1>(ak, wk, bk, kout, 1024, 1024, 8, 2560, bx - 256, cmp, smem);
  } else {
    unsigned char* actb = (unsigned char*)smem;       // 640 B
    int* azs = (int*)(smem + 640);                    // 128 B (4-aligned)
    build_actb(mask, actb, azs, tid);
    cvt_sparse_body(vsrc, vdst, actb, (bx - 2816) * 256 + tid, 2048 * 256);
  }
}

// ---- V projection (CMP=1, V^T output) ----
__global__ __launch_bounds__(256, 4) void gemm_v(
    const unsigned short* __restrict__ av, const unsigned short* __restrict__ wv,
    const float* __restrict__ bv, unsigned short* __restrict__ vout,
    const int* __restrict__ cmp) {
  __shared__ __align__(16) char smem[32768];
  gemm_body<2, 0, 1>(av, wv, bv, vout, 1024, 1024, 8, 2560, (int)blockIdx.x, cmp, smem);
}

// ---- out projection (CMP=0, f32 output) ----
__global__ __launch_bounds__(256, 4) void gemm_out(
    const unsigned short* __restrict__ am, const unsigned short* __restrict__ wo,
    const float* __restrict__ bo, float* __restrict__ oout,
    const int* __restrict__ cmp) {
  __shared__ __align__(16) char smem[32768];
  gemm_body<0, 0, 0>(am, wo, bo, oout, 1024, 1024, 8, 256, (int)blockIdx.x, cmp, smem);
}

// ----------------------------- fused attention -----------------------------
// One block per (h, b); 8 waves, wave w owns q rows [16w,16w+16).
// Swapped-operand MFMAs so q = lane&15 everywhere; online softmax over r.
// LDS (48KB): kv_s[2][K,V] 32KB; pa_s 16KB; q/sa^T staging overlays.
// launch_bounds (512,4): PROVEN config (do not raise min-waves: round-23's
// (512,6) squeezed VGPR 64->40 and spilled).
// Active-review compaction: reviews with mask==1 (when any mask==0 exists in
// row b) have pooled weight exactly 0.0f (expf(-1e30 - max) underflows) ->
// skipped entirely.  Bitmask is uniform per block (depends only on b).
__global__ __launch_bounds__(512, 4) void attn2(
    const unsigned short* __restrict__ qb, const unsigned short* __restrict__ kb,
    const unsigned short* __restrict__ vtg, const int* __restrict__ mask,
    const int* __restrict__ mask2, const float* __restrict__ sa_a,
    const float* __restrict__ sa_b, unsigned short* __restrict__ merged) {
  const int h = (int)blockIdx.x;
  const int b = (int)blockIdx.y;
  const int tid = (int)threadIdx.x;
  const int lane = tid & 63, wave = tid >> 6;
  const int lm = lane & 15, l4 = lane >> 4;
  const int sw = (lm & 7) << 4;

  __shared__ unsigned short kv_s[2][2][64 * 64];  // [buf][0=K [t][d], 1=V^T [d][t]]
  __shared__ unsigned short pa_s[8 * 16 * 64];    // wave-private P/att rows

  char* kvb0 = (char*)kv_s;          // buf stride 16384; V^T at +8192
  char* qreg = (char*)kv_s + 16384;  // q staging region = buf1 (dead after hoist)
  char* satb = (char*)pa_s;          // sa^T staging (dead after hoist)

  // ---- active-review bitmask (uniform across the block) ----
  unsigned am = 0u;
#pragma unroll
  for (int rr = 0; rr < 20; ++rr)
    am |= (mask[b * 20 + rr] == 0) ? (1u << rr) : 0u;
  const unsigned act = am ? am : 0xFFFFFu;

  // ---- stage Q into qreg (pre-swizzled source columns) ----
#pragma unroll
  for (int s = 0; s < 2; ++s) {
    int idx = s * 512 + tid, row = idx >> 3, blk = idx & 7;
    int cb = blk ^ (row & 7);
    gload_lds16(qb + (size_t)(b * 128 + row) * 1024 + h * 64 + cb * 8, qreg + idx * 16);
  }
  // ---- stage sa^T into satb: sat[jj][d] = sa_a[d][jj], swizzled ----
#pragma unroll
  for (int s = 0; s < 8; ++s) {
    int idx = s * 512 + tid, jj = idx & 63, d = idx >> 6;
    *(unsigned short*)(satb + jj * 128 + ((d * 2) ^ ((jj & 7) << 4))) =
        f2bf(sa_a[d * 64 + jj]);
  }
  // ---- stage first ACTIVE review K/V into buf0 ----
  const int srow = tid >> 3, sblk = tid & 7;
  const int scb = sblk ^ (srow & 7);
  int r = (int)__builtin_ctz(act);
  unsigned rem = act & (act - 1u);
  gload_lds16(kb + ((size_t)(b * 20 + r) * 64 + srow) * 1024 + h * 64 + scb * 8,
              kvb0 + tid * 16);
  gload_lds16(vtg + ((size_t)(b * 20 + r) * 16 + h) * 4096 + srow * 64 + scb * 8,
              kvb0 + 8192 + tid * 16);

  f32x4 sbv[4];
#pragma unroll
  for (int i = 0; i < 4; ++i) sbv[i] = *(const f32x4*)(sa_b + i * 16 + l4 * 4);

  __syncthreads();  // qreg, satb, buf0 all visible

  // ---- hoist Q B-fragments and sa^T A-fragments to registers ----
  const char* qrp = qreg + (wave * 16 + lm) * 128;
  bf16x8 qf[2];
  qf[0] = *(const bf16x8*)(qrp + ((l4 * 16) ^ sw));
  qf[1] = *(const bf16x8*)(qrp + ((64 + l4 * 16) ^ sw));
  bf16x8 sfr[2][4];
#pragma unroll
  for (int kk = 0; kk < 2; ++kk)
#pragma unroll
    for (int i = 0; i < 4; ++i)
      sfr[kk][i] = *(const bf16x8*)(satb + (i * 16 + lm) * 128 +
                                    ((kk * 64 + l4 * 16) ^ sw));
  asm volatile("s_waitcnt lgkmcnt(0)" ::: "memory");  // hoist reads retired
  __syncthreads();  // all waves done -> qreg/satb reusable as buf1 / P-rows

  char* pw = (char*)pa_s + wave * 2048 + lm * 128;  // wave-private row q=lm

  f32x4 zero4 = {0.f, 0.f, 0.f, 0.f};
  f32x4 Pacc[4];
#pragma unroll
  for (int i = 0; i < 4; ++i) Pacc[i] = zero4;
  float m_run = -3.0e38f, s_run = 0.0f;

  int it = 0;
  for (;;) {
    const int pb = it & 1;
    if (it) __syncthreads();  // buf[pb] staged; all waves done with buf[1-pb]
    const int nr = rem ? (int)__builtin_ctz(rem) : -1;
    if (nr >= 0) {  // stage next active review (flies under this one's compute)
      const int nbuf = pb ^ 1;
      gload_lds16(kb + ((size_t)(b * 20 + nr) * 64 + srow) * 1024 + h * 64 + scb * 8,
                  kvb0 + nbuf * 16384 + tid * 16);
      gload_lds16(vtg + ((size_t)(b * 20 + nr) * 16 + h) * 4096 + srow * 64 + scb * 8,
                  kvb0 + nbuf * 16384 + 8192 + tid * 16);
    }
    const char* kbse = kvb0 + pb * 16384;
    const char* vbse = kvb0 + pb * 16384 + 8192;

    // ---- mask2 loads issued BEFORE the MFMA cluster (latency hides) ----
    const int mbase = (b * 20 + r) * 64;
    int4 m2v[4];
#pragma unroll
    for (int i = 0; i < 4; ++i)
      m2v[i] = *(const int4*)(mask2 + mbase + i * 16 + l4 * 4);

    // ---- S^T = mfma(K, Q): rows t, col q (q pre-scaled by 1/8) ----
    f32x4 sc[4];
#pragma unroll
    for (int i = 0; i < 4; ++i) sc[i] = zero4;
    __builtin_amdgcn_s_setprio(1);
#pragma unroll
    for (int kk = 0; kk < 2; ++kk) {
      bf16x8 kf[4];
#pragma unroll
      for (int i = 0; i < 4; ++i)
        kf[i] = *(const bf16x8*)(kbse + (i * 16 + lm) * 128 + ((kk * 64 + l4 * 16) ^ sw));
#pragma unroll
      for (int i = 0; i < 4; ++i)
        sc[i] = __builtin_amdgcn_mfma_f32_16x16x32_bf16(kf[i], qf[kk], sc[i], 0, 0, 0);
    }
    __builtin_amdgcn_s_setprio(0);

    // ---- token mask (scores already scaled) + softmax over t ----
#pragma unroll
    for (int i = 0; i < 4; ++i) {
      sc[i][0] = (m2v[i].x == 0) ? -1e20f : sc[i][0];
      sc[i][1] = (m2v[i].y == 0) ? -1e20f : sc[i][1];
      sc[i][2] = (m2v[i].z == 0) ? -1e20f : sc[i][2];
      sc[i][3] = (m2v[i].w == 0) ? -1e20f : sc[i][3];
    }
    float mx = sc[0][0];
#pragma unroll
    for (int i = 0; i < 4; ++i)
#pragma unroll
      for (int p = 0; p < 4; ++p) mx = fmaxf(mx, sc[i][p]);
    mx = fmaxf(mx, __shfl_xor(mx, 16));
    mx = fmaxf(mx, __shfl_xor(mx, 32));
    float sum = 0.f;
#pragma unroll
    for (int i = 0; i < 4; ++i)
#pragma unroll
      for (int p = 0; p < 4; ++p) {
        float e = __expf(sc[i][p] - mx);
        sc[i][p] = e;
        sum += e;
      }
    sum += __shfl_xor(sum, 16);
    sum += __shfl_xor(sum, 32);
    const float pinv = __builtin_amdgcn_rcpf(sum);

    // ---- P -> wave-private LDS [q][t], packed 8B swizzled writes ----
#pragma unroll
    for (int i = 0; i < 4; ++i) {
      uint2 wv;
      wv.x = cvtpk(sc[i][0] * pinv, sc[i][1] * pinv);
      wv.y = cvtpk(sc[i][2] * pinv, sc[i][3] * pinv);
      *(uint2*)(pw + ((i * 32 + l4 * 8) ^ sw)) = wv;
    }

    // ---- att^T = mfma(V^T, P): rows d, col q ----
    f32x4 av[4];
#pragma unroll
    for (int i = 0; i < 4; ++i) av[i] = zero4;
    __builtin_amdgcn_s_setprio(1);
#pragma unroll
    for (int kk = 0; kk < 2; ++kk) {
      bf16x8 pf = *(const bf16x8*)(pw + ((kk * 64 + l4 * 16) ^ sw));
      bf16x8 vf[4];
#pragma unroll
      for (int i = 0; i < 4; ++i)
        vf[i] = *(const bf16x8*)(vbse + (i * 16 + lm) * 128 + ((kk * 64 + l4 * 16) ^ sw));
#pragma unroll
      for (int i = 0; i < 4; ++i)
        av[i] = __builtin_amdgcn_mfma_f32_16x16x32_bf16(vf[i], pf, av[i], 0, 0, 0);
    }
    __builtin_amdgcn_s_setprio(0);

    // ---- att -> same wave-private LDS [q][d] (P already consumed) ----
#pragma unroll
    for (int i = 0; i < 4; ++i) {
      uint2 wv;
      wv.x = cvtpk(av[i][0], av[i][1]);
      wv.y = cvtpk(av[i][2], av[i][3]);
      *(uint2*)(pw + ((i * 32 + l4 * 8) ^ sw)) = wv;
    }

    // ---- e^T = mfma(sa^T, att): rows jj, col q ----
    f32x4 ep[4];
#pragma unroll
    for (int i = 0; i < 4; ++i) ep[i] = zero4;
    __builtin_amdgcn_s_setprio(1);
#pragma unroll
    for (int kk = 0; kk < 2; ++kk) {
      bf16x8 afr = *(const bf16x8*)(pw + ((kk * 64 + l4 * 16) ^ sw));
#pragma unroll
      for (int i = 0; i < 4; ++i)
        ep[i] = __builtin_amdgcn_mfma_f32_16x16x32_bf16(sfr[kk][i], afr, ep[i], 0, 0, 0);
    }
    __builtin_amdgcn_s_setprio(0);
    float a = 0.f;
#pragma unroll
    for (int i = 0; i < 4; ++i)
#pragma unroll
      for (int p = 0; p < 4; ++p) a += fast_tanh(ep[i][p]) * sbv[i][p];
    a += __shfl_xor(a, 16);
    a += __shfl_xor(a, 32);

    // ---- exact online softmax update over active reviews ----
    const float e_r = a;
    const float mnew = fmaxf(m_run, e_r);
    const float scl = __expf(m_run - mnew);
    const float w = __expf(e_r - mnew);
    s_run = s_run * scl + w;
#pragma unroll
    for (int i = 0; i < 4; ++i)
#pragma unroll
      for (int p = 0; p < 4; ++p) Pacc[i][p] = Pacc[i][p] * scl + w * av[i][p];
    m_run = mnew;

    if (nr < 0) break;
    r = nr;
    rem &= rem - 1u;
    ++it;
  }

  // ---- merged[b*128+q][h*64+d] = bf16(Pacc / s) ----
  const float inv_s = __builtin_amdgcn_rcpf(s_run);
  unsigned short* mrow = merged + (size_t)(b * 128 + wave * 16 + lm) * 1024 + h * 64;
#pragma unroll
  for (int i = 0; i < 4; ++i) {
    uint2 o;
    o.x = cvtpk(Pacc[i][0] * inv_s, Pacc[i][1] * inv_s);
    o.y = cvtpk(Pacc[i][2] * inv_s, Pacc[i][3] * inv_s);
    *(uint2*)(mrow + i * 16 + l4 * 4) = o;
  }
}

// ---------------------------------------------------------------------------
extern "C" void kernel_launch(void* const* d_in, const int* in_sizes, int n_in,
                              void* d_out, int out_size, void* d_ws, size_t ws_size,
                              hipStream_t stream) {
  (void)in_sizes; (void)n_in; (void)out_size;
  const float* query = (const float*)d_in[0];
  const float* key   = (const float*)d_in[1];
  const float* value = (const float*)d_in[2];
  const int*   mask  = (const int*)d_in[3];
  const int*   mask2 = (const int*)d_in[4];
  const float* Wq = (const float*)d_in[5];
  const float* bq = (const float*)d_in[6];
  const float* Wk = (const float*)d_in[7];
  const float* bk = (const float*)d_in[8];
  const float* Wv = (const float*)d_in[9];
  const float* bv = (const float*)d_in[10];
  const float* Wo = (const float*)d_in[11];
  const float* bo = (const float*)d_in[12];
  const float* sa_a = (const float*)d_in[13];
  const float* sa_b = (const float*)d_in[14];

  char* ws = (char*)d_ws;
  size_t off = 0;
  auto carve = [&](size_t bytes) -> char* {
    char* p = ws + off;
    off += (bytes + 255) & ~(size_t)255;
    return p;
  };
  unsigned short* wq_b = (unsigned short*)carve((size_t)1024 * 1024 * 2);
  unsigned short* wk_b = (unsigned short*)carve((size_t)1024 * 1024 * 2);
  unsigned short* wv_b = (unsigned short*)carve((size_t)1024 * 1024 * 2);
  unsigned short* wo_b = (unsigned short*)carve((size_t)1024 * 1024 * 2);
  unsigned short* q_b  = (unsigned short*)carve((size_t)4096 * 1024 * 2);
  unsigned short* k_b  = (unsigned short*)carve((size_t)40960 * 1024 * 2);
  unsigned short* vt_g = (unsigned short*)carve((size_t)40960 * 1024 * 2);
  unsigned short* mrg  = (unsigned short*)carve((size_t)4096 * 1024 * 2);
  int* cmp = (int*)carve(4096);
  unsigned short* act = (unsigned short*)carve((size_t)40960 * 1024 * 2);
  unsigned short* act_q = (unsigned short*)carve((size_t)4096 * 1024 * 2);

  const size_t actv_bytes = (size_t)40960 * 1024 * 2;
  const bool fat = ws_size >= off + actv_bytes + (1 << 20);

  // prep: weights cvt + Q cvt + compaction + K sparse-cvt, one dispatch
  prep<<<4097, 256, 0, stream>>>(Wq, Wk, Wv, Wo, wq_b, wk_b, wv_b, wo_b,
                                 query, act_q, key, act, mask, cmp);

  if (fat) {
    // Q + K projections + V sparse-cvt in one dispatch (cvt rides the tail)
    unsigned short* act_v = (unsigned short*)carve(actv_bytes);
    gemm_qkv<<<256 + 2560 + 2048, 256, 0, stream>>>(
        act_q, wq_b, bq, q_b, act, wk_b, bk, k_b, value, act_v, mask, cmp);
    gemm_v<<<2560, 256, 0, stream>>>(act_v, wv_b, bv, vt_g, cmp);
  } else {
    gemm_qk<<<256 + 2560, 256, 0, stream>>>(act_q, wq_b, bq, q_b,
                                            act, wk_b, bk, k_b, cmp);
    cvt_sp<<<2048, 256, 0, stream>>>(value, act, mask);
    gemm_v<<<2560, 256, 0, stream>>>(act, wv_b, bv, vt_g, cmp);
  }

  attn2<<<dim3(16, 32), 512, 0, stream>>>(q_b, k_b, vt_g, mask, mask2, sa_a, sa_b, mrg);

  gemm_out<<<256, 256, 0, stream>>>(mrg, wo_b, bo, (float*)d_out, cmp);
}